// Round 2
// baseline (2277.738 us; speedup 1.0000x reference)
//
#include <hip/hip_runtime.h>
#include <hip/hip_bf16.h>

#define DIN 8192
#define HH 4096
#define BLT 2048   // total tokens (2*1024)
#define LSEQ 1024

typedef unsigned short u16;
typedef __bf16 bf16x8 __attribute__((ext_vector_type(8)));
typedef float f32x4v __attribute__((ext_vector_type(4)));

__device__ __forceinline__ u16 f2b(float f) {
  unsigned u = __float_as_uint(f);
  u += 0x7fff + ((u >> 16) & 1);
  return (u16)(u >> 16);
}
__device__ __forceinline__ float b2f(u16 h) {
  return __uint_as_float(((unsigned)h) << 16);
}

__device__ __forceinline__ void gl_lds16(const u16* g, u16* l) {
  __builtin_amdgcn_global_load_lds(
      (const __attribute__((address_space(1))) void*)g,
      (__attribute__((address_space(3))) void*)l, 16, 0, 0);
}

// ---------------- f32 -> bf16 convert (vectorized, grid-stride) ----------------
__global__ void cvt_kernel(const float* __restrict__ in, u16* __restrict__ out, long n) {
  long i = ((long)blockIdx.x * blockDim.x + threadIdx.x) * 4;
  long stride = (long)gridDim.x * blockDim.x * 4;
  for (; i < n; i += stride) {
    f32x4v v = *(const f32x4v*)(in + i);
    ushort4 o;
    o.x = f2b(v[0]); o.y = f2b(v[1]); o.z = f2b(v[2]); o.w = f2b(v[3]);
    *(ushort4*)(out + i) = o;
  }
}

// convert with row padding (W_x 288 rows -> 384 rows, pad rows = 0)
__global__ void cvt_pad_kernel(const float* __restrict__ in, u16* __restrict__ out,
                               int rows_in, int cols, long n_out) {
  long i = ((long)blockIdx.x * blockDim.x + threadIdx.x) * 4;
  long stride = (long)gridDim.x * blockDim.x * 4;
  for (; i < n_out; i += stride) {
    long r = i / cols;
    long c = i - r * cols;
    ushort4 o;
    if (r < rows_in) {
      f32x4v v = *(const f32x4v*)(in + r * cols + c);
      o.x = f2b(v[0]); o.y = f2b(v[1]); o.z = f2b(v[2]); o.w = f2b(v[3]);
    } else {
      o.x = 0; o.y = 0; o.z = 0; o.w = 0;
    }
    *(ushort4*)(out + i) = o;
  }
}

// ---------------- bf16 MFMA GEMM, C[m][n] = sum_k A[m][k]*B[n][k] ----------------
// A: [M][K] row-major bf16, B: [N][K] row-major bf16. M%128==0, N%128==0, K%32==0.
// m97 structure: 128x128 tile, BK=32, 4 waves (each 64x64), global_load_lds w=16.
template<int OUTBF>
__global__ __launch_bounds__(256) void gemm_bt(
    const u16* __restrict__ A, const u16* __restrict__ B, void* __restrict__ Cp,
    int M, int N, int K)
{
  __shared__ __align__(16) u16 As[128 * 32];
  __shared__ __align__(16) u16 Bs[128 * 32];
  const int tid = threadIdx.x;
  const int wave = tid >> 6;
  const int lane = tid & 63;
  const int wr = wave >> 1;   // 0..1
  const int wc = wave & 1;    // 0..1
  const long m0 = (long)blockIdx.y * 128;
  const long n0 = (long)blockIdx.x * 128;
  const int fr = lane & 15;
  const int fq = lane >> 4;

  f32x4v acc[4][4];
#pragma unroll
  for (int i = 0; i < 4; ++i)
#pragma unroll
    for (int j = 0; j < 4; ++j) acc[i][j] = (f32x4v){0.f, 0.f, 0.f, 0.f};

  for (int k0 = 0; k0 < K; k0 += 32) {
    // stage A,B tiles: 128x32 bf16 each = 8KB = 512 x 16B slots; 2 issues/thread/tile
#pragma unroll
    for (int i = 0; i < 2; ++i) {
      const int idx = tid + i * 256;
      const int row = idx >> 2;
      const int seg = idx & 3;
      gl_lds16(A + (m0 + row) * (long)K + k0 + seg * 8, As + (i * 256 + wave * 64) * 8);
      gl_lds16(B + (n0 + row) * (long)K + k0 + seg * 8, Bs + (i * 256 + wave * 64) * 8);
    }
    __syncthreads();
    bf16x8 af[4], bfr[4];
#pragma unroll
    for (int mi = 0; mi < 4; ++mi)
      af[mi] = *(const bf16x8*)(As + (wr * 64 + mi * 16 + fr) * 32 + fq * 8);
#pragma unroll
    for (int ni = 0; ni < 4; ++ni)
      bfr[ni] = *(const bf16x8*)(Bs + (wc * 64 + ni * 16 + fr) * 32 + fq * 8);
#pragma unroll
    for (int mi = 0; mi < 4; ++mi)
#pragma unroll
      for (int ni = 0; ni < 4; ++ni)
        acc[mi][ni] = __builtin_amdgcn_mfma_f32_16x16x32_bf16(af[mi], bfr[ni], acc[mi][ni], 0, 0, 0);
    __syncthreads();
  }

  // epilogue: C/D layout col = lane&15, row = 4*(lane>>4)+r
#pragma unroll
  for (int mi = 0; mi < 4; ++mi) {
#pragma unroll
    for (int ni = 0; ni < 4; ++ni) {
      const long col = n0 + wc * 64 + ni * 16 + fr;
#pragma unroll
      for (int r = 0; r < 4; ++r) {
        const long rowi = m0 + wr * 64 + mi * 16 + fq * 4 + r;
        if constexpr (OUTBF) {
          ((u16*)Cp)[rowi * N + col] = f2b(acc[mi][ni][r]);
        } else {
          ((float*)Cp)[rowi * N + col] = acc[mi][ni][r];
        }
      }
    }
  }
}

// ---------------- causal depthwise conv (K=4) + SiLU, proj(bf16) -> x(bf16) ------
__global__ __launch_bounds__(256) void conv_silu_kernel(
    const u16* __restrict__ proj, const float* __restrict__ conv_w,
    const float* __restrict__ conv_b, u16* __restrict__ xb)
{
  const int idx = blockIdx.x * 256 + threadIdx.x;  // 2048 tokens * 2048 d-quads
  const int tok = idx >> 11;
  const int dq = (idx & 2047) << 2;
  const int l = tok & (LSEQ - 1);
  f32x4v cb = *(const f32x4v*)(conv_b + dq);
  float a0 = cb[0], a1 = cb[1], a2 = cb[2], a3 = cb[3];
  f32x4v w0 = *(const f32x4v*)(conv_w + (size_t)(dq + 0) * 4);
  f32x4v w1 = *(const f32x4v*)(conv_w + (size_t)(dq + 1) * 4);
  f32x4v w2 = *(const f32x4v*)(conv_w + (size_t)(dq + 2) * 4);
  f32x4v w3 = *(const f32x4v*)(conv_w + (size_t)(dq + 3) * 4);
#pragma unroll
  for (int j = 0; j < 4; ++j) {
    const int lj = l - 3 + j;
    if (lj >= 0) {
      ushort4 xv = *(const ushort4*)(proj + (size_t)(tok - 3 + j) * 16384 + dq);
      a0 = fmaf(w0[j], b2f(xv.x), a0);
      a1 = fmaf(w1[j], b2f(xv.y), a1);
      a2 = fmaf(w2[j], b2f(xv.z), a2);
      a3 = fmaf(w3[j], b2f(xv.w), a3);
    }
  }
  ushort4 o;
  o.x = f2b(a0 / (1.f + __expf(-a0)));
  o.y = f2b(a1 / (1.f + __expf(-a1)));
  o.z = f2b(a2 / (1.f + __expf(-a2)));
  o.w = f2b(a3 / (1.f + __expf(-a3)));
  *(ushort4*)(xb + (size_t)tok * DIN + dq) = o;
}

// ---------------- RMS norm of ts(256), Bm(16), Cm(16) per token ----------------
__global__ __launch_bounds__(64) void rms_kernel(
    const float* __restrict__ ssm, u16* __restrict__ tsb,
    float* __restrict__ Bn, float* __restrict__ Cn)
{
  const int tok = blockIdx.x;
  const int lane = threadIdx.x;
  const float* row = ssm + (size_t)tok * 384;
  f32x4v t = *(const f32x4v*)(row + lane * 4);
  float ss = t[0]*t[0] + t[1]*t[1] + t[2]*t[2] + t[3]*t[3];
#pragma unroll
  for (int o = 32; o; o >>= 1) ss += __shfl_xor(ss, o);
  const float sc = rsqrtf(ss * (1.f / 256.f) + 1e-6f);
  ushort4 o4;
  o4.x = f2b(t[0] * sc); o4.y = f2b(t[1] * sc);
  o4.z = f2b(t[2] * sc); o4.w = f2b(t[3] * sc);
  *(ushort4*)(tsb + (size_t)tok * 256 + lane * 4) = o4;

  float v = 0.f;
  if (lane < 32) v = row[256 + lane];
  float g = v * v;
#pragma unroll
  for (int o = 1; o < 16; o <<= 1) g += __shfl_xor(g, o);
  const float scBC = rsqrtf(g * (1.f / 16.f) + 1e-6f);
  if (lane < 16) Bn[(size_t)tok * 16 + lane] = v * scBC;
  else if (lane < 32) Cn[(size_t)tok * 16 + (lane - 16)] = v * scBC;
}

// ---------------- selective scan: 4 lanes per (b,d) channel ----------------
// fuses: softplus(dtmm+b_dt), u from x(bf16), y=scan+u*D, *silu(gate), ->bf16
__global__ void __launch_bounds__(256) scan_kernel(
    const float* __restrict__ dtmm, const float* __restrict__ b_dt,
    const u16* __restrict__ xbf, const float* __restrict__ Bn,
    const float* __restrict__ Cn, const float* __restrict__ A_log,
    const float* __restrict__ Dv, const u16* __restrict__ proj,
    u16* __restrict__ yg)
{
  const int tid = threadIdx.x;
  const int g = blockIdx.x * 64 + (tid >> 2);  // channel 0..16383
  const int ln = tid & 3;
  const int b = g >> 13;
  const int d = g & (DIN - 1);
  float a[4];
#pragma unroll
  for (int j = 0; j < 4; ++j) a[j] = -__expf(A_log[(size_t)d * 16 + ln * 4 + j]);
  const float Dd = Dv[d];
  const float bdt = b_dt[d];
  float s0 = 0.f, s1 = 0.f, s2 = 0.f, s3 = 0.f;
  const long tokbase = (long)b * LSEQ;
  for (int l = 0; l < LSEQ; ++l) {
    const long tok = tokbase + l;
    const float z = dtmm[tok * DIN + d] + bdt;
    const float dt = (z > 20.f) ? z : log1pf(__expf(z));
    const float u = b2f(xbf[tok * DIN + d]);
    f32x4v Bv = *(const f32x4v*)(Bn + tok * 16 + ln * 4);
    f32x4v Cv = *(const f32x4v*)(Cn + tok * 16 + ln * 4);
    const float dtu = dt * u;
    float y = 0.f;
    float e0 = __expf(dt * a[0]);
    float e1 = __expf(dt * a[1]);
    float e2 = __expf(dt * a[2]);
    float e3 = __expf(dt * a[3]);
    s0 = fmaf(s0, e0, dtu * Bv[0]); y = fmaf(s0, Cv[0], y);
    s1 = fmaf(s1, e1, dtu * Bv[1]); y = fmaf(s1, Cv[1], y);
    s2 = fmaf(s2, e2, dtu * Bv[2]); y = fmaf(s2, Cv[2], y);
    s3 = fmaf(s3, e3, dtu * Bv[3]); y = fmaf(s3, Cv[3], y);
    y += __shfl_xor(y, 1);
    y += __shfl_xor(y, 2);
    if (ln == 0) {
      const float yt = fmaf(u, Dd, y);
      const float gt = b2f(proj[tok * 16384 + DIN + d]);
      const float sg = gt / (1.f + __expf(-gt));
      yg[tok * DIN + d] = f2b(yt * sg);
    }
  }
}

extern "C" void kernel_launch(void* const* d_in, const int* in_sizes, int n_in,
                              void* d_out, int out_size, void* d_ws, size_t ws_size,
                              hipStream_t stream) {
  const float* hs     = (const float*)d_in[0];
  const float* W_in   = (const float*)d_in[1];
  const float* conv_w = (const float*)d_in[2];
  const float* conv_b = (const float*)d_in[3];
  const float* W_x    = (const float*)d_in[4];
  const float* W_dt   = (const float*)d_in[5];
  const float* b_dt   = (const float*)d_in[6];
  const float* A_log  = (const float*)d_in[7];
  const float* Dv     = (const float*)d_in[8];
  const float* W_out  = (const float*)d_in[9];
  float* out = (float*)d_out;

  char* ws = (char*)d_ws;
  size_t off = 0;
  auto alloc = [&](size_t bytes) -> char* {
    char* p = ws + off;
    off += (bytes + 255) & ~(size_t)255;
    return p;
  };

  // R1: 134MB — W_in_bf16 during GEMM1; afterwards dtmm(f32,67MB)+W_out_bf16(67MB)
  u16* W_in_b = (u16*)alloc(134217728);
  // R2: 16.8MB — hs_bf16 during GEMM1; afterwards ssm/ts/Bn/Cn/W_dt
  u16* hs_b = (u16*)alloc(16777216);
  u16* proj_b = (u16*)alloc((size_t)BLT * 16384 * 2);  // 67MB, lives to scan end (gate)
  u16* x_b    = (u16*)alloc((size_t)BLT * DIN * 2);    // 33.5MB
  u16* W_xp_b = (u16*)alloc((size_t)384 * DIN * 2);    // 6.3MB
  u16* yg_b   = (u16*)alloc((size_t)BLT * DIN * 2);    // 33.5MB

  float* dtmm   = (float*)W_in_b;                        // [0,67MB) of R1
  u16*   W_out_b= (u16*)((char*)W_in_b + 67108864);      // [67MB,134MB) of R1
  float* ssm    = (float*)hs_b;                          // 3,145,728 B
  u16*   ts_b   = (u16*)((char*)hs_b + 3145728);         // 1,048,576 B
  float* Bn     = (float*)((char*)hs_b + 3145728 + 1048576);
  float* Cn     = (float*)((char*)hs_b + 3145728 + 1048576 + 131072);
  u16*   W_dt_b = (u16*)((char*)hs_b + 3145728 + 1048576 + 262144);  // 4,194,304 B

  const int CG = 2048;
  // 1) convert GEMM1 operands
  cvt_kernel<<<CG, 256, 0, stream>>>(W_in, W_in_b, 67108864L);
  cvt_kernel<<<CG, 256, 0, stream>>>(hs, hs_b, 8388608L);
  // 2) proj = hs @ W_in^T  (2048 x 16384, K=4096), bf16 out
  gemm_bt<1><<<dim3(16384 / 128, BLT / 128), 256, 0, stream>>>(hs_b, W_in_b, proj_b, BLT, 16384, 4096);
  // 3) now R1/R2 free: convert remaining weights
  cvt_kernel<<<CG, 256, 0, stream>>>(W_out, W_out_b, 33554432L);
  cvt_kernel<<<CG, 256, 0, stream>>>(W_dt, W_dt_b, 2097152L);
  cvt_pad_kernel<<<CG, 256, 0, stream>>>(W_x, W_xp_b, 288, DIN, (long)384 * DIN);
  // 4) conv + silu -> x (bf16)
  conv_silu_kernel<<<16384, 256, 0, stream>>>(proj_b, conv_w, conv_b, x_b);
  // 5) ssm = x @ W_x^T (padded to 384 cols), f32 out
  gemm_bt<0><<<dim3(384 / 128, BLT / 128), 256, 0, stream>>>(x_b, W_xp_b, ssm, BLT, 384, DIN);
  // 6) rms norms
  rms_kernel<<<BLT, 64, 0, stream>>>(ssm, ts_b, Bn, Cn);
  // 7) dtmm = ts_rms @ W_dt^T (2048 x 8192, K=256), f32 out
  gemm_bt<0><<<dim3(DIN / 128, BLT / 128), 256, 0, stream>>>(ts_b, W_dt_b, dtmm, BLT, DIN, 256);
  // 8) selective scan (fuses softplus, +x*D, gate silu, bf16 cast)
  scan_kernel<<<256, 256, 0, stream>>>(dtmm, b_dt, x_b, Bn, Cn, A_log, Dv, proj_b, yg_b);
  // 9) out = ygated @ W_out^T (2048 x 4096, K=8192), f32 out
  gemm_bt<0><<<dim3(HH / 128, BLT / 128), 256, 0, stream>>>(yg_b, W_out_b, out, BLT, HH, DIN);
}

// Round 4
// 1243.921 us; speedup vs baseline: 1.8311x; 1.8311x over previous
//
#include <hip/hip_runtime.h>
#include <hip/hip_bf16.h>

#define DIN 8192
#define HH 4096
#define BLT 2048   // total tokens (2*1024)
#define LSEQ 1024
#define CL 64      // scan chunk length
#define NCG 32     // total chunks (16 per batch)

typedef unsigned short u16;
typedef __bf16 bf16x8 __attribute__((ext_vector_type(8)));
typedef float f32x4v __attribute__((ext_vector_type(4)));

__device__ __forceinline__ u16 f2b(float f) {
  unsigned u = __float_as_uint(f);
  u += 0x7fff + ((u >> 16) & 1);
  return (u16)(u >> 16);
}
__device__ __forceinline__ float b2f(u16 h) {
  return __uint_as_float(((unsigned)h) << 16);
}

__device__ __forceinline__ void gl_lds16(const u16* g, u16* l) {
  __builtin_amdgcn_global_load_lds(
      (const __attribute__((address_space(1))) void*)g,
      (__attribute__((address_space(3))) void*)l, 16, 0, 0);
}

// ---------------- f32 -> bf16 convert (vectorized, grid-stride) ----------------
__global__ void cvt_kernel(const float* __restrict__ in, u16* __restrict__ out, long n) {
  long i = ((long)blockIdx.x * blockDim.x + threadIdx.x) * 4;
  long stride = (long)gridDim.x * blockDim.x * 4;
  for (; i < n; i += stride) {
    f32x4v v = *(const f32x4v*)(in + i);
    ushort4 o;
    o.x = f2b(v[0]); o.y = f2b(v[1]); o.z = f2b(v[2]); o.w = f2b(v[3]);
    *(ushort4*)(out + i) = o;
  }
}

// convert with row padding (W_x 288 rows -> 384 rows, pad rows = 0)
__global__ void cvt_pad_kernel(const float* __restrict__ in, u16* __restrict__ out,
                               int rows_in, int cols, long n_out) {
  long i = ((long)blockIdx.x * blockDim.x + threadIdx.x) * 4;
  long stride = (long)gridDim.x * blockDim.x * 4;
  for (; i < n_out; i += stride) {
    long r = i / cols;
    long c = i - r * cols;
    ushort4 o;
    if (r < rows_in) {
      f32x4v v = *(const f32x4v*)(in + r * cols + c);
      o.x = f2b(v[0]); o.y = f2b(v[1]); o.z = f2b(v[2]); o.w = f2b(v[3]);
    } else {
      o.x = 0; o.y = 0; o.z = 0; o.w = 0;
    }
    *(ushort4*)(out + i) = o;
  }
}

// ---------------- bf16 MFMA GEMM, C[m][n] = sum_k A[m][k]*B[n][k] ----------------
// MODE 0: f32 out [M][N].  MODE 1: bf16 out [M][N].
// MODE 2: f32 out TRANSPOSED [N][M] with fused softplus(acc + bias[n]) (dt path).
template<int MODE>
__global__ __launch_bounds__(256) void gemm_bt(
    const u16* __restrict__ A, const u16* __restrict__ B, void* __restrict__ Cp,
    int M, int N, int K, const float* __restrict__ bias = nullptr)
{
  __shared__ __align__(16) u16 As[128 * 32];
  __shared__ __align__(16) u16 Bs[128 * 32];
  const int tid = threadIdx.x;
  const int wave = tid >> 6;
  const int lane = tid & 63;
  const int wr = wave >> 1;   // 0..1
  const int wc = wave & 1;    // 0..1
  const long m0 = (long)blockIdx.y * 128;
  const long n0 = (long)blockIdx.x * 128;
  const int fr = lane & 15;
  const int fq = lane >> 4;

  f32x4v acc[4][4];
#pragma unroll
  for (int i = 0; i < 4; ++i)
#pragma unroll
    for (int j = 0; j < 4; ++j) acc[i][j] = (f32x4v){0.f, 0.f, 0.f, 0.f};

  for (int k0 = 0; k0 < K; k0 += 32) {
#pragma unroll
    for (int i = 0; i < 2; ++i) {
      const int idx = tid + i * 256;
      const int row = idx >> 2;
      const int seg = idx & 3;
      gl_lds16(A + (m0 + row) * (long)K + k0 + seg * 8, As + (i * 256 + wave * 64) * 8);
      gl_lds16(B + (n0 + row) * (long)K + k0 + seg * 8, Bs + (i * 256 + wave * 64) * 8);
    }
    __syncthreads();
    bf16x8 af[4], bfr[4];
#pragma unroll
    for (int mi = 0; mi < 4; ++mi)
      af[mi] = *(const bf16x8*)(As + (wr * 64 + mi * 16 + fr) * 32 + fq * 8);
#pragma unroll
    for (int ni = 0; ni < 4; ++ni)
      bfr[ni] = *(const bf16x8*)(Bs + (wc * 64 + ni * 16 + fr) * 32 + fq * 8);
#pragma unroll
    for (int mi = 0; mi < 4; ++mi)
#pragma unroll
      for (int ni = 0; ni < 4; ++ni)
        acc[mi][ni] = __builtin_amdgcn_mfma_f32_16x16x32_bf16(af[mi], bfr[ni], acc[mi][ni], 0, 0, 0);
    __syncthreads();
  }

  // epilogue: C/D layout col = lane&15, row = 4*(lane>>4)+r
#pragma unroll
  for (int mi = 0; mi < 4; ++mi) {
#pragma unroll
    for (int ni = 0; ni < 4; ++ni) {
      const long col = n0 + wc * 64 + ni * 16 + fr;
#pragma unroll
      for (int r = 0; r < 4; ++r) {
        const long rowi = m0 + wr * 64 + mi * 16 + fq * 4 + r;
        if constexpr (MODE == 1) {
          ((u16*)Cp)[rowi * N + col] = f2b(acc[mi][ni][r]);
        } else if constexpr (MODE == 0) {
          ((float*)Cp)[rowi * N + col] = acc[mi][ni][r];
        } else {
          const float z = acc[mi][ni][r] + bias[col];
          const float dtv = (z > 20.f) ? z : log1pf(__expf(z));
          ((float*)Cp)[col * (long)M + rowi] = dtv;  // transposed [N][M]
        }
      }
    }
  }
}

// ---------------- causal depthwise conv (K=4) + SiLU, proj(bf16) -> x(bf16) ------
__global__ __launch_bounds__(256) void conv_silu_kernel(
    const u16* __restrict__ proj, const float* __restrict__ conv_w,
    const float* __restrict__ conv_b, u16* __restrict__ xb)
{
  const int idx = blockIdx.x * 256 + threadIdx.x;  // 2048 tokens * 2048 d-quads
  const int tok = idx >> 11;
  const int dq = (idx & 2047) << 2;
  const int l = tok & (LSEQ - 1);
  f32x4v cb = *(const f32x4v*)(conv_b + dq);
  float a0 = cb[0], a1 = cb[1], a2 = cb[2], a3 = cb[3];
  f32x4v w0 = *(const f32x4v*)(conv_w + (size_t)(dq + 0) * 4);
  f32x4v w1 = *(const f32x4v*)(conv_w + (size_t)(dq + 1) * 4);
  f32x4v w2 = *(const f32x4v*)(conv_w + (size_t)(dq + 2) * 4);
  f32x4v w3 = *(const f32x4v*)(conv_w + (size_t)(dq + 3) * 4);
#pragma unroll
  for (int j = 0; j < 4; ++j) {
    const int lj = l - 3 + j;
    if (lj >= 0) {
      ushort4 xv = *(const ushort4*)(proj + (size_t)(tok - 3 + j) * 16384 + dq);
      a0 = fmaf(w0[j], b2f(xv.x), a0);
      a1 = fmaf(w1[j], b2f(xv.y), a1);
      a2 = fmaf(w2[j], b2f(xv.z), a2);
      a3 = fmaf(w3[j], b2f(xv.w), a3);
    }
  }
  ushort4 o;
  o.x = f2b(a0 / (1.f + __expf(-a0)));
  o.y = f2b(a1 / (1.f + __expf(-a1)));
  o.z = f2b(a2 / (1.f + __expf(-a2)));
  o.w = f2b(a3 / (1.f + __expf(-a3)));
  *(ushort4*)(xb + (size_t)tok * DIN + dq) = o;
}

// ---------------- x [2048][8192] -> x_T [8192][2048] (4x4 register transpose) ----
__global__ __launch_bounds__(256) void transpose_x_kernel(
    const u16* __restrict__ in, u16* __restrict__ outp)
{
  const int t = threadIdx.x;
  const int sr = t >> 4, sc = t & 15;
  const long r0 = (long)blockIdx.x * 64 + sr * 4;   // token
  const long c0 = (long)blockIdx.y * 64 + sc * 4;   // d
  ushort4 v[4];
#pragma unroll
  for (int i = 0; i < 4; ++i)
    v[i] = *(const ushort4*)(in + (r0 + i) * DIN + c0);
#pragma unroll
  for (int i = 0; i < 4; ++i) {
    ushort4 o;
    o.x = ((const u16*)&v[0])[i];
    o.y = ((const u16*)&v[1])[i];
    o.z = ((const u16*)&v[2])[i];
    o.w = ((const u16*)&v[3])[i];
    *(ushort4*)(outp + (c0 + i) * BLT + r0) = o;
  }
}

// ---------------- RMS norm of ts(256), Bm(16), Cm(16) per token ----------------
__global__ __launch_bounds__(64) void rms_kernel(
    const float* __restrict__ ssm, u16* __restrict__ tsb,
    float* __restrict__ Bn, float* __restrict__ Cn)
{
  const int tok = blockIdx.x;
  const int lane = threadIdx.x;
  const float* row = ssm + (size_t)tok * 384;
  f32x4v t = *(const f32x4v*)(row + lane * 4);
  float ss = t[0]*t[0] + t[1]*t[1] + t[2]*t[2] + t[3]*t[3];
#pragma unroll
  for (int o = 32; o; o >>= 1) ss += __shfl_xor(ss, o);
  const float sc = rsqrtf(ss * (1.f / 256.f) + 1e-6f);
  ushort4 o4;
  o4.x = f2b(t[0] * sc); o4.y = f2b(t[1] * sc);
  o4.z = f2b(t[2] * sc); o4.w = f2b(t[3] * sc);
  *(ushort4*)(tsb + (size_t)tok * 256 + lane * 4) = o4;

  float v = 0.f;
  if (lane < 32) v = row[256 + lane];
  float g = v * v;
#pragma unroll
  for (int o = 1; o < 16; o <<= 1) g += __shfl_xor(g, o);
  const float scBC = rsqrtf(g * (1.f / 16.f) + 1e-6f);
  if (lane < 16) Bn[(size_t)tok * 16 + lane] = v * scBC;
  else if (lane < 32) Cn[(size_t)tok * 16 + (lane - 16)] = v * scBC;
}

// ---------------- chunked scan phase 1: per-chunk partials (E, S) ----------------
// task = (d, chunk); 4 lanes per d (each 4 n's). dt_T/x_T are [DIN][BLT].
__global__ __launch_bounds__(256) void scan_p1_kernel(
    const float* __restrict__ dtT, const u16* __restrict__ xT,
    const float* __restrict__ Bn, const float* __restrict__ A_log,
    float* __restrict__ partE, float* __restrict__ partS)
{
  __shared__ float Bsh[CL][16];
  const int tid = threadIdx.x;
  const int chunk = blockIdx.y;
  const int d = blockIdx.x * 64 + (tid >> 2);
  const int ln = tid & 3;
  const int tok0 = chunk * CL;
  {
    const int tt = tid >> 2, q = tid & 3;
    *(f32x4v*)&Bsh[tt][q * 4] = *(const f32x4v*)(Bn + (size_t)(tok0 + tt) * 16 + q * 4);
  }
  __syncthreads();
  float a[4];
#pragma unroll
  for (int j = 0; j < 4; ++j) a[j] = -__expf(A_log[(size_t)d * 16 + ln * 4 + j]);
  float E0 = 1.f, E1 = 1.f, E2 = 1.f, E3 = 1.f;
  float S0 = 0.f, S1 = 0.f, S2 = 0.f, S3 = 0.f;
  const float* dtp = dtT + (size_t)d * BLT + tok0;
  const u16* xp = xT + (size_t)d * BLT + tok0;
  for (int l = 0; l < CL; l += 4) {
    f32x4v dt4 = *(const f32x4v*)(dtp + l);
    ushort4 u4 = *(const ushort4*)(xp + l);
#pragma unroll
    for (int i = 0; i < 4; ++i) {
      const float dt = dt4[i];
      const float u = b2f(((const u16*)&u4)[i]);
      const float dtu = dt * u;
      f32x4v Bv = *(const f32x4v*)&Bsh[l + i][ln * 4];
      const float e0 = __expf(dt * a[0]);
      const float e1 = __expf(dt * a[1]);
      const float e2 = __expf(dt * a[2]);
      const float e3 = __expf(dt * a[3]);
      S0 = fmaf(S0, e0, dtu * Bv[0]); E0 *= e0;
      S1 = fmaf(S1, e1, dtu * Bv[1]); E1 *= e1;
      S2 = fmaf(S2, e2, dtu * Bv[2]); E2 *= e2;
      S3 = fmaf(S3, e3, dtu * Bv[3]); E3 *= e3;
    }
  }
  const size_t off = (size_t)chunk * (DIN * 16) + (size_t)d * 16 + ln * 4;
  f32x4v Ev = {E0, E1, E2, E3}, Sv = {S0, S1, S2, S3};
  *(f32x4v*)(partE + off) = Ev;
  *(f32x4v*)(partS + off) = Sv;
}

// ---------------- chunked scan phase 2: combine chunk partials ----------------
// one lane per (d, n); rewrites partS[c] with the state ENTERING chunk c.
__global__ __launch_bounds__(256) void scan_p2_kernel(
    const float* __restrict__ partE, float* __restrict__ partS)
{
  const int dn = blockIdx.x * 256 + threadIdx.x;  // 0..131071
  float s = 0.f;
  for (int c = 0; c < NCG; ++c) {
    if ((c & 15) == 0) s = 0.f;  // batch boundary reset (c==0, c==16)
    const size_t off = (size_t)c * (DIN * 16) + dn;
    const float e = partE[off];
    const float ps = partS[off];
    partS[off] = s;
    s = fmaf(e, s, ps);
  }
}

// ---------------- chunked scan phase 3: re-scan with true init, emit y ----------
__global__ __launch_bounds__(256) void scan_p3_kernel(
    const float* __restrict__ dtT, const u16* __restrict__ xT,
    const float* __restrict__ Bn, const float* __restrict__ Cn,
    const float* __restrict__ A_log, const float* __restrict__ Dv,
    const float* __restrict__ stateIn, const u16* __restrict__ proj,
    u16* __restrict__ yg)
{
  __shared__ float Bsh[CL][16], Csh[CL][16];
  const int tid = threadIdx.x;
  const int chunk = blockIdx.y;
  const int d = blockIdx.x * 64 + (tid >> 2);
  const int ln = tid & 3;
  const int tok0 = chunk * CL;
  {
    const int tt = tid >> 2, q = tid & 3;
    *(f32x4v*)&Bsh[tt][q * 4] = *(const f32x4v*)(Bn + (size_t)(tok0 + tt) * 16 + q * 4);
    *(f32x4v*)&Csh[tt][q * 4] = *(const f32x4v*)(Cn + (size_t)(tok0 + tt) * 16 + q * 4);
  }
  __syncthreads();
  float a[4];
#pragma unroll
  for (int j = 0; j < 4; ++j) a[j] = -__expf(A_log[(size_t)d * 16 + ln * 4 + j]);
  f32x4v sv = *(const f32x4v*)(stateIn + (size_t)chunk * (DIN * 16) + (size_t)d * 16 + ln * 4);
  float S0 = sv[0], S1 = sv[1], S2 = sv[2], S3 = sv[3];
  const float Dd = Dv[d];
  const float* dtp = dtT + (size_t)d * BLT + tok0;
  const u16* xp = xT + (size_t)d * BLT + tok0;
  for (int l = 0; l < CL; l += 4) {
    f32x4v dt4 = *(const f32x4v*)(dtp + l);
    ushort4 u4 = *(const ushort4*)(xp + l);
#pragma unroll
    for (int i = 0; i < 4; ++i) {
      const float dt = dt4[i];
      const float u = b2f(((const u16*)&u4)[i]);
      const float dtu = dt * u;
      f32x4v Bv = *(const f32x4v*)&Bsh[l + i][ln * 4];
      f32x4v Cv = *(const f32x4v*)&Csh[l + i][ln * 4];
      const float e0 = __expf(dt * a[0]);
      const float e1 = __expf(dt * a[1]);
      const float e2 = __expf(dt * a[2]);
      const float e3 = __expf(dt * a[3]);
      float y;
      S0 = fmaf(S0, e0, dtu * Bv[0]); y = S0 * Cv[0];
      S1 = fmaf(S1, e1, dtu * Bv[1]); y = fmaf(S1, Cv[1], y);
      S2 = fmaf(S2, e2, dtu * Bv[2]); y = fmaf(S2, Cv[2], y);
      S3 = fmaf(S3, e3, dtu * Bv[3]); y = fmaf(S3, Cv[3], y);
      y += __shfl_xor(y, 1);
      y += __shfl_xor(y, 2);
      if (ln == 0) {
        const long tok = tok0 + l + i;
        const float yt = fmaf(u, Dd, y);
        const float gt = b2f(proj[tok * 16384 + DIN + d]);
        const float sg = gt / (1.f + __expf(-gt));
        yg[tok * DIN + d] = f2b(yt * sg);
      }
    }
  }
}

extern "C" void kernel_launch(void* const* d_in, const int* in_sizes, int n_in,
                              void* d_out, int out_size, void* d_ws, size_t ws_size,
                              hipStream_t stream) {
  const float* hs     = (const float*)d_in[0];
  const float* W_in   = (const float*)d_in[1];
  const float* conv_w = (const float*)d_in[2];
  const float* conv_b = (const float*)d_in[3];
  const float* W_x    = (const float*)d_in[4];
  const float* W_dt   = (const float*)d_in[5];
  const float* b_dt   = (const float*)d_in[6];
  const float* A_log  = (const float*)d_in[7];
  const float* Dv     = (const float*)d_in[8];
  const float* W_out  = (const float*)d_in[9];
  float* out = (float*)d_out;

  char* ws = (char*)d_ws;
  size_t off = 0;
  auto alloc = [&](size_t bytes) -> char* {
    char* p = ws + off;
    off += (bytes + 255) & ~(size_t)255;
    return p;
  };

  // R1: 134MB — W_in_bf16 during GEMM1; afterwards dt_T(f32,67MB)+W_out_bf16(67MB)
  u16* W_in_b = (u16*)alloc(134217728);
  // R2: 16.8MB — hs_bf16 during GEMM1; afterwards ssm/ts/Bn/Cn/W_dt
  u16* hs_b = (u16*)alloc(16777216);
  u16* proj_b = (u16*)alloc((size_t)BLT * 16384 * 2);  // 67MB, lives to scan end (gate)
  u16* x_b    = (u16*)alloc((size_t)BLT * DIN * 2);    // 33.5MB; after GEMM5: partE+partS
  u16* W_xp_b = (u16*)alloc((size_t)384 * DIN * 2);    // 6.3MB
  u16* yg_b   = (u16*)alloc((size_t)BLT * DIN * 2);    // 33.5MB
  u16* x_T    = (u16*)alloc((size_t)BLT * DIN * 2);    // 33.5MB [DIN][BLT]

  float* dt_T   = (float*)W_in_b;                        // [0,67MB) of R1: [DIN][BLT]
  u16*   W_out_b= (u16*)((char*)W_in_b + 67108864);      // [67MB,134MB) of R1
  float* ssm    = (float*)hs_b;                          // 3,145,728 B
  u16*   ts_b   = (u16*)((char*)hs_b + 3145728);         // 1,048,576 B
  float* Bn     = (float*)((char*)hs_b + 3145728 + 1048576);
  float* Cn     = (float*)((char*)hs_b + 3145728 + 1048576 + 131072);
  u16*   W_dt_b = (u16*)((char*)hs_b + 3145728 + 1048576 + 262144);  // 4,194,304 B
  float* partE  = (float*)x_b;                           // 16.8MB (x_b dead post-GEMM5)
  float* partS  = (float*)((char*)x_b + 16777216);       // 16.8MB

  const int CG = 2048;
  // 1) convert GEMM1 operands
  cvt_kernel<<<CG, 256, 0, stream>>>(W_in, W_in_b, 67108864L);
  cvt_kernel<<<CG, 256, 0, stream>>>(hs, hs_b, 8388608L);
  // 2) proj = hs @ W_in^T  (2048 x 16384, K=4096), bf16 out
  gemm_bt<1><<<dim3(16384 / 128, BLT / 128), 256, 0, stream>>>(hs_b, W_in_b, proj_b, BLT, 16384, 4096, nullptr);
  // 3) now R1/R2 free: convert remaining weights
  cvt_kernel<<<CG, 256, 0, stream>>>(W_out, W_out_b, 33554432L);
  cvt_kernel<<<CG, 256, 0, stream>>>(W_dt, W_dt_b, 2097152L);
  cvt_pad_kernel<<<CG, 256, 0, stream>>>(W_x, W_xp_b, 288, DIN, (long)384 * DIN);
  // 4) conv + silu -> x (bf16)
  conv_silu_kernel<<<16384, 256, 0, stream>>>(proj_b, conv_w, conv_b, x_b);
  // 5) x_T = transpose(x)  [DIN][BLT]
  transpose_x_kernel<<<dim3(BLT / 64, DIN / 64), 256, 0, stream>>>(x_b, x_T);
  // 6) ssm = x @ W_x^T (padded to 384 cols), f32 out
  gemm_bt<0><<<dim3(384 / 128, BLT / 128), 256, 0, stream>>>(x_b, W_xp_b, ssm, BLT, 384, DIN, nullptr);
  // 7) rms norms
  rms_kernel<<<BLT, 64, 0, stream>>>(ssm, ts_b, Bn, Cn);
  // 8) dt_T = softplus(ts_rms @ W_dt^T + b_dt), f32 TRANSPOSED [DIN][BLT]
  gemm_bt<2><<<dim3(DIN / 128, BLT / 128), 256, 0, stream>>>(ts_b, W_dt_b, dt_T, BLT, DIN, 256, b_dt);
  // 9) chunked scan: partials -> combine -> emit (fuses D-residual, gate silu, bf16)
  scan_p1_kernel<<<dim3(DIN / 64, NCG), 256, 0, stream>>>(dt_T, x_T, Bn, A_log, partE, partS);
  scan_p2_kernel<<<DIN * 16 / 256, 256, 0, stream>>>(partE, partS);
  scan_p3_kernel<<<dim3(DIN / 64, NCG), 256, 0, stream>>>(dt_T, x_T, Bn, Cn, A_log, Dv, partS, proj_b, yg_b);
  // 10) out = ygated @ W_out^T (2048 x 4096, K=8192), f32 out
  gemm_bt<0><<<dim3(HH / 128, BLT / 128), 256, 0, stream>>>(yg_b, W_out_b, out, BLT, HH, DIN, nullptr);
}

// Round 5
// 1188.327 us; speedup vs baseline: 1.9168x; 1.0468x over previous
//
#include <hip/hip_runtime.h>
#include <hip/hip_bf16.h>

#define DIN 8192
#define HH 4096
#define BLT 2048   // total tokens (2*1024)
#define LSEQ 1024
#define CL 64      // scan chunk length
#define NCG 32     // total chunks (16 per batch)

typedef unsigned short u16;
typedef __bf16 bf16x8 __attribute__((ext_vector_type(8)));
typedef float f32x4v __attribute__((ext_vector_type(4)));

__device__ __forceinline__ u16 f2b(float f) {
  unsigned u = __float_as_uint(f);
  u += 0x7fff + ((u >> 16) & 1);
  return (u16)(u >> 16);
}
__device__ __forceinline__ float b2f(u16 h) {
  return __uint_as_float(((unsigned)h) << 16);
}

__device__ __forceinline__ void gl_lds16(const u16* g, u16* l) {
  __builtin_amdgcn_global_load_lds(
      (const __attribute__((address_space(1))) void*)g,
      (__attribute__((address_space(3))) void*)l, 16, 0, 0);
}

// ---------------- f32 -> bf16 convert (vectorized, grid-stride) ----------------
__global__ void cvt_kernel(const float* __restrict__ in, u16* __restrict__ out, long n) {
  long i = ((long)blockIdx.x * blockDim.x + threadIdx.x) * 4;
  long stride = (long)gridDim.x * blockDim.x * 4;
  for (; i < n; i += stride) {
    f32x4v v = *(const f32x4v*)(in + i);
    ushort4 o;
    o.x = f2b(v[0]); o.y = f2b(v[1]); o.z = f2b(v[2]); o.w = f2b(v[3]);
    *(ushort4*)(out + i) = o;
  }
}

// convert with row padding (W_x 288 rows -> 384 rows, pad rows = 0)
__global__ void cvt_pad_kernel(const float* __restrict__ in, u16* __restrict__ out,
                               int rows_in, int cols, long n_out) {
  long i = ((long)blockIdx.x * blockDim.x + threadIdx.x) * 4;
  long stride = (long)gridDim.x * blockDim.x * 4;
  for (; i < n_out; i += stride) {
    long r = i / cols;
    long c = i - r * cols;
    ushort4 o;
    if (r < rows_in) {
      f32x4v v = *(const f32x4v*)(in + r * cols + c);
      o.x = f2b(v[0]); o.y = f2b(v[1]); o.z = f2b(v[2]); o.w = f2b(v[3]);
    } else {
      o.x = 0; o.y = 0; o.z = 0; o.w = 0;
    }
    *(ushort4*)(out + i) = o;
  }
}

// ---------------- m97-style 128x128 GEMM (kept for small/odd shapes) -----------
// MODE 0: f32 out [M][N].  MODE 2: f32 out TRANSPOSED [N][M], fused softplus+bias.
template<int MODE>
__global__ __launch_bounds__(256) void gemm_bt(
    const u16* __restrict__ A, const u16* __restrict__ B, void* __restrict__ Cp,
    int M, int N, int K, const float* __restrict__ bias = nullptr)
{
  __shared__ __align__(16) u16 As[128 * 32];
  __shared__ __align__(16) u16 Bs[128 * 32];
  const int tid = threadIdx.x;
  const int wave = tid >> 6;
  const int lane = tid & 63;
  const int wr = wave >> 1;
  const int wc = wave & 1;
  const long m0 = (long)blockIdx.y * 128;
  const long n0 = (long)blockIdx.x * 128;
  const int fr = lane & 15;
  const int fq = lane >> 4;

  f32x4v acc[4][4];
#pragma unroll
  for (int i = 0; i < 4; ++i)
#pragma unroll
    for (int j = 0; j < 4; ++j) acc[i][j] = (f32x4v){0.f, 0.f, 0.f, 0.f};

  for (int k0 = 0; k0 < K; k0 += 32) {
#pragma unroll
    for (int i = 0; i < 2; ++i) {
      const int idx = tid + i * 256;
      const int row = idx >> 2;
      const int seg = idx & 3;
      gl_lds16(A + (m0 + row) * (long)K + k0 + seg * 8, As + (i * 256 + wave * 64) * 8);
      gl_lds16(B + (n0 + row) * (long)K + k0 + seg * 8, Bs + (i * 256 + wave * 64) * 8);
    }
    __syncthreads();
    bf16x8 af[4], bfr[4];
#pragma unroll
    for (int mi = 0; mi < 4; ++mi)
      af[mi] = *(const bf16x8*)(As + (wr * 64 + mi * 16 + fr) * 32 + fq * 8);
#pragma unroll
    for (int ni = 0; ni < 4; ++ni)
      bfr[ni] = *(const bf16x8*)(Bs + (wc * 64 + ni * 16 + fr) * 32 + fq * 8);
#pragma unroll
    for (int mi = 0; mi < 4; ++mi)
#pragma unroll
      for (int ni = 0; ni < 4; ++ni)
        acc[mi][ni] = __builtin_amdgcn_mfma_f32_16x16x32_bf16(af[mi], bfr[ni], acc[mi][ni], 0, 0, 0);
    __syncthreads();
  }

#pragma unroll
  for (int mi = 0; mi < 4; ++mi) {
#pragma unroll
    for (int ni = 0; ni < 4; ++ni) {
      const long col = n0 + wc * 64 + ni * 16 + fr;
#pragma unroll
      for (int r = 0; r < 4; ++r) {
        const long rowi = m0 + wr * 64 + mi * 16 + fq * 4 + r;
        if constexpr (MODE == 0) {
          ((float*)Cp)[rowi * N + col] = acc[mi][ni][r];
        } else {
          const float z = acc[mi][ni][r] + bias[col];
          const float dtv = (z > 20.f) ? z : log1pf(__expf(z));
          ((float*)Cp)[col * (long)M + rowi] = dtv;  // transposed [N][M]
        }
      }
    }
  }
}

// ---------------- 256x256 8-wave phase-split GEMM (T1+T3+T4+T5) ----------------
// C[m][n] = sum_k A[m][k]*B[n][k]; M%256==0, N%256==0, K%64==0. grid.x % 8 == 0.
// 8 waves as 2(m) x 4(n); per-wave output 128x64; BK=32; LDS 64KB double-buffered.
// Counted vmcnt(4): tile t+1's 4 loads stay in flight across barriers.
template<int OUTBF>
__global__ __launch_bounds__(512, 2) void gemm256(
    const u16* __restrict__ A, const u16* __restrict__ B, void* __restrict__ Cp,
    int M, int N, int K)
{
  __shared__ __align__(16) u16 lds[2][2][8192];  // [buf][A=0/B=1][256 rows][32 k]
  const int tid = threadIdx.x;
  const int lane = tid & 63;
  const int wid = tid >> 6;
  const int wm = wid >> 2;   // 0..1
  const int wn = wid & 3;    // 0..3
  const int fr = lane & 15;
  const int fq = lane >> 4;

  // XCD-aware swizzle: blocks resident on one XCD get consecutive logical tiles
  const int nbx = N >> 8;
  const int cpx = gridDim.x >> 3;
  const int bid = blockIdx.x;
  const int swz = (bid & 7) * cpx + (bid >> 3);
  const long m0 = (long)(swz / nbx) << 8;
  const long n0 = (long)(swz % nbx) << 8;

  // staging: 512 threads x 16B covers 8KB; each operand-tile (16KB) = 2 issues
  const int srow = tid >> 2;           // 0..127
  const int sseg = tid & 3;
  const u16* ag0 = A + (m0 + srow) * (long)K + sseg * 8;
  const u16* ag1 = ag0 + 128 * (long)K;
  const u16* bg0 = B + (n0 + srow) * (long)K + sseg * 8;
  const u16* bg1 = bg0 + 128 * (long)K;

  auto stage = [&](int c, int koff) {
    gl_lds16(ag0 + koff, &lds[c][0][tid * 8]);
    gl_lds16(ag1 + koff, &lds[c][0][4096 + tid * 8]);
    gl_lds16(bg0 + koff, &lds[c][1][tid * 8]);
    gl_lds16(bg1 + koff, &lds[c][1][4096 + tid * 8]);
  };

  const int NT = K >> 5;
  stage(0, 0);
  stage(1, 32);
  asm volatile("s_waitcnt vmcnt(4)" ::: "memory");  // tile0 landed (own loads)
  __builtin_amdgcn_s_barrier();                     // -> landed for all waves

  f32x4v acc[8][4];
#pragma unroll
  for (int i = 0; i < 8; ++i)
#pragma unroll
    for (int j = 0; j < 4; ++j) acc[i][j] = (f32x4v){0.f, 0.f, 0.f, 0.f};

  const int aoff = (wm * 128 + fr) * 32 + fq * 8;  // +mi*512 per m-rep
  const int boff = (wn * 64 + fr) * 32 + fq * 8;   // +ni*512 per n-rep
  bf16x8 af[4], bfg[4];

  for (int t = 0; t < NT; ++t) {
    const int c = t & 1;
    const u16* Asl = &lds[c][0][0];
    const u16* Bsl = &lds[c][1][0];
    // ---- phase 0: frags m0-3 + all B; MFMA upper half ----
#pragma unroll
    for (int mi = 0; mi < 4; ++mi) af[mi] = *(const bf16x8*)(Asl + aoff + mi * 512);
#pragma unroll
    for (int ni = 0; ni < 4; ++ni) bfg[ni] = *(const bf16x8*)(Bsl + boff + ni * 512);
    __builtin_amdgcn_s_barrier();
    asm volatile("s_waitcnt lgkmcnt(0)" ::: "memory");
    __builtin_amdgcn_s_setprio(1);
#pragma unroll
    for (int mi = 0; mi < 4; ++mi)
#pragma unroll
      for (int ni = 0; ni < 4; ++ni)
        acc[mi][ni] = __builtin_amdgcn_mfma_f32_16x16x32_bf16(af[mi], bfg[ni], acc[mi][ni], 0, 0, 0);
    __builtin_amdgcn_s_setprio(0);
    __builtin_amdgcn_s_barrier();
    // ---- phase 1: frags m4-7; stage tile t+2 into buf c; MFMA lower half ----
#pragma unroll
    for (int mi = 0; mi < 4; ++mi) af[mi] = *(const bf16x8*)(Asl + aoff + 2048 + mi * 512);
    asm volatile("s_waitcnt lgkmcnt(0)" ::: "memory");  // this wave's reads of buf c done
    __builtin_amdgcn_s_barrier();                       // ALL waves' reads done -> buf c reusable
    if (t + 2 < NT) stage(c, (t + 2) * 32);
    __builtin_amdgcn_s_setprio(1);
#pragma unroll
    for (int mi = 0; mi < 4; ++mi)
#pragma unroll
      for (int ni = 0; ni < 4; ++ni)
        acc[mi + 4][ni] = __builtin_amdgcn_mfma_f32_16x16x32_bf16(af[mi], bfg[ni], acc[mi + 4][ni], 0, 0, 0);
    __builtin_amdgcn_s_setprio(0);
    if (t + 2 < NT) {
      asm volatile("s_waitcnt vmcnt(4)" ::: "memory");  // tile t+1 landed; t+2 in flight
    } else {
      asm volatile("s_waitcnt vmcnt(0)" ::: "memory");  // drain tail
    }
    __builtin_amdgcn_s_barrier();
  }

#pragma unroll
  for (int mi = 0; mi < 8; ++mi) {
#pragma unroll
    for (int ni = 0; ni < 4; ++ni) {
      const long col = n0 + wn * 64 + ni * 16 + fr;
      const long rbase = m0 + wm * 128 + mi * 16 + fq * 4;
#pragma unroll
      for (int r = 0; r < 4; ++r) {
        if constexpr (OUTBF) {
          ((u16*)Cp)[(rbase + r) * N + col] = f2b(acc[mi][ni][r]);
        } else {
          ((float*)Cp)[(rbase + r) * N + col] = acc[mi][ni][r];
        }
      }
    }
  }
}

// ---------------- causal depthwise conv (K=4) + SiLU, proj(bf16) -> x(bf16) ------
__global__ __launch_bounds__(256) void conv_silu_kernel(
    const u16* __restrict__ proj, const float* __restrict__ conv_w,
    const float* __restrict__ conv_b, u16* __restrict__ xb)
{
  const int idx = blockIdx.x * 256 + threadIdx.x;
  const int tok = idx >> 11;
  const int dq = (idx & 2047) << 2;
  const int l = tok & (LSEQ - 1);
  f32x4v cb = *(const f32x4v*)(conv_b + dq);
  float a0 = cb[0], a1 = cb[1], a2 = cb[2], a3 = cb[3];
  f32x4v w0 = *(const f32x4v*)(conv_w + (size_t)(dq + 0) * 4);
  f32x4v w1 = *(const f32x4v*)(conv_w + (size_t)(dq + 1) * 4);
  f32x4v w2 = *(const f32x4v*)(conv_w + (size_t)(dq + 2) * 4);
  f32x4v w3 = *(const f32x4v*)(conv_w + (size_t)(dq + 3) * 4);
#pragma unroll
  for (int j = 0; j < 4; ++j) {
    const int lj = l - 3 + j;
    if (lj >= 0) {
      ushort4 xv = *(const ushort4*)(proj + (size_t)(tok - 3 + j) * 16384 + dq);
      a0 = fmaf(w0[j], b2f(xv.x), a0);
      a1 = fmaf(w1[j], b2f(xv.y), a1);
      a2 = fmaf(w2[j], b2f(xv.z), a2);
      a3 = fmaf(w3[j], b2f(xv.w), a3);
    }
  }
  ushort4 o;
  o.x = f2b(a0 / (1.f + __expf(-a0)));
  o.y = f2b(a1 / (1.f + __expf(-a1)));
  o.z = f2b(a2 / (1.f + __expf(-a2)));
  o.w = f2b(a3 / (1.f + __expf(-a3)));
  *(ushort4*)(xb + (size_t)tok * DIN + dq) = o;
}

// ---------------- x [2048][8192] -> x_T [8192][2048] (4x4 register transpose) ----
__global__ __launch_bounds__(256) void transpose_x_kernel(
    const u16* __restrict__ in, u16* __restrict__ outp)
{
  const int t = threadIdx.x;
  const int sr = t >> 4, sc = t & 15;
  const long r0 = (long)blockIdx.x * 64 + sr * 4;
  const long c0 = (long)blockIdx.y * 64 + sc * 4;
  ushort4 v[4];
#pragma unroll
  for (int i = 0; i < 4; ++i)
    v[i] = *(const ushort4*)(in + (r0 + i) * DIN + c0);
#pragma unroll
  for (int i = 0; i < 4; ++i) {
    ushort4 o;
    o.x = ((const u16*)&v[0])[i];
    o.y = ((const u16*)&v[1])[i];
    o.z = ((const u16*)&v[2])[i];
    o.w = ((const u16*)&v[3])[i];
    *(ushort4*)(outp + (c0 + i) * BLT + r0) = o;
  }
}

// ---------------- RMS norm of ts(256), Bm(16), Cm(16) per token ----------------
__global__ __launch_bounds__(64) void rms_kernel(
    const float* __restrict__ ssm, u16* __restrict__ tsb,
    float* __restrict__ Bn, float* __restrict__ Cn)
{
  const int tok = blockIdx.x;
  const int lane = threadIdx.x;
  const float* row = ssm + (size_t)tok * 384;
  f32x4v t = *(const f32x4v*)(row + lane * 4);
  float ss = t[0]*t[0] + t[1]*t[1] + t[2]*t[2] + t[3]*t[3];
#pragma unroll
  for (int o = 32; o; o >>= 1) ss += __shfl_xor(ss, o);
  const float sc = rsqrtf(ss * (1.f / 256.f) + 1e-6f);
  ushort4 o4;
  o4.x = f2b(t[0] * sc); o4.y = f2b(t[1] * sc);
  o4.z = f2b(t[2] * sc); o4.w = f2b(t[3] * sc);
  *(ushort4*)(tsb + (size_t)tok * 256 + lane * 4) = o4;

  float v = 0.f;
  if (lane < 32) v = row[256 + lane];
  float g = v * v;
#pragma unroll
  for (int o = 1; o < 16; o <<= 1) g += __shfl_xor(g, o);
  const float scBC = rsqrtf(g * (1.f / 16.f) + 1e-6f);
  if (lane < 16) Bn[(size_t)tok * 16 + lane] = v * scBC;
  else if (lane < 32) Cn[(size_t)tok * 16 + (lane - 16)] = v * scBC;
}

// ---------------- chunked scan phase 1: per-chunk partials (E, S) ----------------
__global__ __launch_bounds__(256) void scan_p1_kernel(
    const float* __restrict__ dtT, const u16* __restrict__ xT,
    const float* __restrict__ Bn, const float* __restrict__ A_log,
    float* __restrict__ partE, float* __restrict__ partS)
{
  __shared__ float Bsh[CL][16];
  const int tid = threadIdx.x;
  const int chunk = blockIdx.y;
  const int d = blockIdx.x * 64 + (tid >> 2);
  const int ln = tid & 3;
  const int tok0 = chunk * CL;
  {
    const int tt = tid >> 2, q = tid & 3;
    *(f32x4v*)&Bsh[tt][q * 4] = *(const f32x4v*)(Bn + (size_t)(tok0 + tt) * 16 + q * 4);
  }
  __syncthreads();
  float a[4];
#pragma unroll
  for (int j = 0; j < 4; ++j) a[j] = -__expf(A_log[(size_t)d * 16 + ln * 4 + j]);
  float E0 = 1.f, E1 = 1.f, E2 = 1.f, E3 = 1.f;
  float S0 = 0.f, S1 = 0.f, S2 = 0.f, S3 = 0.f;
  const float* dtp = dtT + (size_t)d * BLT + tok0;
  const u16* xp = xT + (size_t)d * BLT + tok0;
  for (int l = 0; l < CL; l += 4) {
    f32x4v dt4 = *(const f32x4v*)(dtp + l);
    ushort4 u4 = *(const ushort4*)(xp + l);
#pragma unroll
    for (int i = 0; i < 4; ++i) {
      const float dt = dt4[i];
      const float u = b2f(((const u16*)&u4)[i]);
      const float dtu = dt * u;
      f32x4v Bv = *(const f32x4v*)&Bsh[l + i][ln * 4];
      const float e0 = __expf(dt * a[0]);
      const float e1 = __expf(dt * a[1]);
      const float e2 = __expf(dt * a[2]);
      const float e3 = __expf(dt * a[3]);
      S0 = fmaf(S0, e0, dtu * Bv[0]); E0 *= e0;
      S1 = fmaf(S1, e1, dtu * Bv[1]); E1 *= e1;
      S2 = fmaf(S2, e2, dtu * Bv[2]); E2 *= e2;
      S3 = fmaf(S3, e3, dtu * Bv[3]); E3 *= e3;
    }
  }
  const size_t off = (size_t)chunk * (DIN * 16) + (size_t)d * 16 + ln * 4;
  f32x4v Ev = {E0, E1, E2, E3}, Sv = {S0, S1, S2, S3};
  *(f32x4v*)(partE + off) = Ev;
  *(f32x4v*)(partS + off) = Sv;
}

// ---------------- chunked scan phase 2: combine chunk partials ----------------
__global__ __launch_bounds__(256) void scan_p2_kernel(
    const float* __restrict__ partE, float* __restrict__ partS)
{
  const int dn = blockIdx.x * 256 + threadIdx.x;
  float s = 0.f;
  for (int c = 0; c < NCG; ++c) {
    if ((c & 15) == 0) s = 0.f;  // batch boundary reset
    const size_t off = (size_t)c * (DIN * 16) + dn;
    const float e = partE[off];
    const float ps = partS[off];
    partS[off] = s;
    s = fmaf(e, s, ps);
  }
}

// ---------------- chunked scan phase 3: re-scan with true init, emit y ----------
__global__ __launch_bounds__(256) void scan_p3_kernel(
    const float* __restrict__ dtT, const u16* __restrict__ xT,
    const float* __restrict__ Bn, const float* __restrict__ Cn,
    const float* __restrict__ A_log, const float* __restrict__ Dv,
    const float* __restrict__ stateIn, const u16* __restrict__ proj,
    u16* __restrict__ yg)
{
  __shared__ float Bsh[CL][16], Csh[CL][16];
  const int tid = threadIdx.x;
  const int chunk = blockIdx.y;
  const int d = blockIdx.x * 64 + (tid >> 2);
  const int ln = tid & 3;
  const int tok0 = chunk * CL;
  {
    const int tt = tid >> 2, q = tid & 3;
    *(f32x4v*)&Bsh[tt][q * 4] = *(const f32x4v*)(Bn + (size_t)(tok0 + tt) * 16 + q * 4);
    *(f32x4v*)&Csh[tt][q * 4] = *(const f32x4v*)(Cn + (size_t)(tok0 + tt) * 16 + q * 4);
  }
  __syncthreads();
  float a[4];
#pragma unroll
  for (int j = 0; j < 4; ++j) a[j] = -__expf(A_log[(size_t)d * 16 + ln * 4 + j]);
  f32x4v sv = *(const f32x4v*)(stateIn + (size_t)chunk * (DIN * 16) + (size_t)d * 16 + ln * 4);
  float S0 = sv[0], S1 = sv[1], S2 = sv[2], S3 = sv[3];
  const float Dd = Dv[d];
  const float* dtp = dtT + (size_t)d * BLT + tok0;
  const u16* xp = xT + (size_t)d * BLT + tok0;
  for (int l = 0; l < CL; l += 4) {
    f32x4v dt4 = *(const f32x4v*)(dtp + l);
    ushort4 u4 = *(const ushort4*)(xp + l);
#pragma unroll
    for (int i = 0; i < 4; ++i) {
      const float dt = dt4[i];
      const float u = b2f(((const u16*)&u4)[i]);
      const float dtu = dt * u;
      f32x4v Bv = *(const f32x4v*)&Bsh[l + i][ln * 4];
      f32x4v Cv = *(const f32x4v*)&Csh[l + i][ln * 4];
      const float e0 = __expf(dt * a[0]);
      const float e1 = __expf(dt * a[1]);
      const float e2 = __expf(dt * a[2]);
      const float e3 = __expf(dt * a[3]);
      float y;
      S0 = fmaf(S0, e0, dtu * Bv[0]); y = S0 * Cv[0];
      S1 = fmaf(S1, e1, dtu * Bv[1]); y = fmaf(S1, Cv[1], y);
      S2 = fmaf(S2, e2, dtu * Bv[2]); y = fmaf(S2, Cv[2], y);
      S3 = fmaf(S3, e3, dtu * Bv[3]); y = fmaf(S3, Cv[3], y);
      y += __shfl_xor(y, 1);
      y += __shfl_xor(y, 2);
      if (ln == 0) {
        const long tok = tok0 + l + i;
        const float yt = fmaf(u, Dd, y);
        const float gt = b2f(proj[tok * 16384 + DIN + d]);
        const float sg = gt / (1.f + __expf(-gt));
        yg[tok * DIN + d] = f2b(yt * sg);
      }
    }
  }
}

extern "C" void kernel_launch(void* const* d_in, const int* in_sizes, int n_in,
                              void* d_out, int out_size, void* d_ws, size_t ws_size,
                              hipStream_t stream) {
  const float* hs     = (const float*)d_in[0];
  const float* W_in   = (const float*)d_in[1];
  const float* conv_w = (const float*)d_in[2];
  const float* conv_b = (const float*)d_in[3];
  const float* W_x    = (const float*)d_in[4];
  const float* W_dt   = (const float*)d_in[5];
  const float* b_dt   = (const float*)d_in[6];
  const float* A_log  = (const float*)d_in[7];
  const float* Dv     = (const float*)d_in[8];
  const float* W_out  = (const float*)d_in[9];
  float* out = (float*)d_out;

  char* ws = (char*)d_ws;
  size_t off = 0;
  auto alloc = [&](size_t bytes) -> char* {
    char* p = ws + off;
    off += (bytes + 255) & ~(size_t)255;
    return p;
  };

  u16* W_in_b = (u16*)alloc(134217728);                // R1: W_in_bf16 -> dt_T + W_out_b
  u16* hs_b = (u16*)alloc(16777216);                   // R2: hs_bf16 -> ssm/ts/Bn/Cn/W_dt
  u16* proj_b = (u16*)alloc((size_t)BLT * 16384 * 2);  // 67MB, lives to scan end (gate)
  u16* x_b    = (u16*)alloc((size_t)BLT * DIN * 2);    // 33.5MB; after GEMM5: partE+partS
  u16* W_xp_b = (u16*)alloc((size_t)384 * DIN * 2);    // 6.3MB
  u16* yg_b   = (u16*)alloc((size_t)BLT * DIN * 2);    // 33.5MB
  u16* x_T    = (u16*)alloc((size_t)BLT * DIN * 2);    // 33.5MB [DIN][BLT]

  float* dt_T   = (float*)W_in_b;
  u16*   W_out_b= (u16*)((char*)W_in_b + 67108864);
  float* ssm    = (float*)hs_b;
  u16*   ts_b   = (u16*)((char*)hs_b + 3145728);
  float* Bn     = (float*)((char*)hs_b + 3145728 + 1048576);
  float* Cn     = (float*)((char*)hs_b + 3145728 + 1048576 + 131072);
  u16*   W_dt_b = (u16*)((char*)hs_b + 3145728 + 1048576 + 262144);
  float* partE  = (float*)x_b;
  float* partS  = (float*)((char*)x_b + 16777216);

  const int CG = 2048;
  // 1) convert GEMM1 operands
  cvt_kernel<<<CG, 256, 0, stream>>>(W_in, W_in_b, 67108864L);
  cvt_kernel<<<CG, 256, 0, stream>>>(hs, hs_b, 8388608L);
  // 2) proj = hs @ W_in^T  (2048 x 16384, K=4096), bf16 out  [256^2 pipelined]
  gemm256<1><<<(16384 / 256) * (BLT / 256), 512, 0, stream>>>(hs_b, W_in_b, proj_b, BLT, 16384, 4096);
  // 3) convert remaining weights
  cvt_kernel<<<CG, 256, 0, stream>>>(W_out, W_out_b, 33554432L);
  cvt_kernel<<<CG, 256, 0, stream>>>(W_dt, W_dt_b, 2097152L);
  cvt_pad_kernel<<<CG, 256, 0, stream>>>(W_x, W_xp_b, 288, DIN, (long)384 * DIN);
  // 4) conv + silu -> x (bf16)
  conv_silu_kernel<<<16384, 256, 0, stream>>>(proj_b, conv_w, conv_b, x_b);
  // 5) x_T = transpose(x)  [DIN][BLT]
  transpose_x_kernel<<<dim3(BLT / 64, DIN / 64), 256, 0, stream>>>(x_b, x_T);
  // 6) ssm = x @ W_x^T (padded to 384 cols), f32 out
  gemm_bt<0><<<dim3(384 / 128, BLT / 128), 256, 0, stream>>>(x_b, W_xp_b, ssm, BLT, 384, DIN, nullptr);
  // 7) rms norms
  rms_kernel<<<BLT, 64, 0, stream>>>(ssm, ts_b, Bn, Cn);
  // 8) dt_T = softplus(ts_rms @ W_dt^T + b_dt), f32 TRANSPOSED [DIN][BLT]
  gemm_bt<2><<<dim3(DIN / 128, BLT / 128), 256, 0, stream>>>(ts_b, W_dt_b, dt_T, BLT, DIN, 256, b_dt);
  // 9) chunked scan
  scan_p1_kernel<<<dim3(DIN / 64, NCG), 256, 0, stream>>>(dt_T, x_T, Bn, A_log, partE, partS);
  scan_p2_kernel<<<DIN * 16 / 256, 256, 0, stream>>>(partE, partS);
  scan_p3_kernel<<<dim3(DIN / 64, NCG), 256, 0, stream>>>(dt_T, x_T, Bn, Cn, A_log, Dv, partS, proj_b, yg_b);
  // 10) out = ygated @ W_out^T (2048 x 4096, K=8192), f32 out  [256^2 pipelined]
  gemm256<0><<<(HH / 256) * (BLT / 256), 512, 0, stream>>>(yg_b, W_out_b, out, BLT, HH, DIN);
}

// Round 6
// 1188.151 us; speedup vs baseline: 1.9170x; 1.0001x over previous
//
#include <hip/hip_runtime.h>
#include <hip/hip_bf16.h>

#define DIN 8192
#define HH 4096
#define BLT 2048   // total tokens (2*1024)
#define LSEQ 1024
#define CL 64      // scan chunk length
#define NCG 32     // total chunks (16 per batch)

typedef unsigned short u16;
typedef __bf16 bf16x8 __attribute__((ext_vector_type(8)));
typedef float f32x4v __attribute__((ext_vector_type(4)));

__device__ __forceinline__ u16 f2b(float f) {
  unsigned u = __float_as_uint(f);
  u += 0x7fff + ((u >> 16) & 1);
  return (u16)(u >> 16);
}
__device__ __forceinline__ float b2f(u16 h) {
  return __uint_as_float(((unsigned)h) << 16);
}

__device__ __forceinline__ void gl_lds16(const u16* g, u16* l) {
  __builtin_amdgcn_global_load_lds(
      (const __attribute__((address_space(1))) void*)g,
      (__attribute__((address_space(3))) void*)l, 16, 0, 0);
}

// bank swizzle: LDS slot (row, slot) holds global seg (slot ^ s(row)),
// s(row) = (row&3)^((row>>2)&3).  Read at fs = fq ^ s(fr).
__device__ __forceinline__ int bsw(int r) { return (r & 3) ^ ((r >> 2) & 3); }

// ---------------- f32 -> bf16 convert (vectorized, grid-stride) ----------------
__global__ void cvt_kernel(const float* __restrict__ in, u16* __restrict__ out, long n) {
  long i = ((long)blockIdx.x * blockDim.x + threadIdx.x) * 4;
  long stride = (long)gridDim.x * blockDim.x * 4;
  for (; i < n; i += stride) {
    f32x4v v = *(const f32x4v*)(in + i);
    ushort4 o;
    o.x = f2b(v[0]); o.y = f2b(v[1]); o.z = f2b(v[2]); o.w = f2b(v[3]);
    *(ushort4*)(out + i) = o;
  }
}

// convert with row padding (W_x 288 rows -> 384 rows, pad rows = 0)
__global__ void cvt_pad_kernel(const float* __restrict__ in, u16* __restrict__ out,
                               int rows_in, int cols, long n_out) {
  long i = ((long)blockIdx.x * blockDim.x + threadIdx.x) * 4;
  long stride = (long)gridDim.x * blockDim.x * 4;
  for (; i < n_out; i += stride) {
    long r = i / cols;
    long c = i - r * cols;
    ushort4 o;
    if (r < rows_in) {
      f32x4v v = *(const f32x4v*)(in + r * cols + c);
      o.x = f2b(v[0]); o.y = f2b(v[1]); o.z = f2b(v[2]); o.w = f2b(v[3]);
    } else {
      o.x = 0; o.y = 0; o.z = 0; o.w = 0;
    }
    *(ushort4*)(out + i) = o;
  }
}

// ---------------- m97-style 128x128 GEMM (small/odd shapes), T2-swizzled -------
// MODE 0: f32 out [M][N].  MODE 2: f32 out TRANSPOSED [N][M], fused softplus+bias.
template<int MODE>
__global__ __launch_bounds__(256) void gemm_bt(
    const u16* __restrict__ A, const u16* __restrict__ B, void* __restrict__ Cp,
    int M, int N, int K, const float* __restrict__ bias = nullptr)
{
  __shared__ __align__(16) u16 As[128 * 32];
  __shared__ __align__(16) u16 Bs[128 * 32];
  const int tid = threadIdx.x;
  const int wave = tid >> 6;
  const int lane = tid & 63;
  const int wr = wave >> 1;
  const int wc = wave & 1;
  const long m0 = (long)blockIdx.y * 128;
  const long n0 = (long)blockIdx.x * 128;
  const int fr = lane & 15;
  const int fq = lane >> 4;
  const int fs = fq ^ bsw(fr);   // swizzled k-seg for fragment reads

  f32x4v acc[4][4];
#pragma unroll
  for (int i = 0; i < 4; ++i)
#pragma unroll
    for (int j = 0; j < 4; ++j) acc[i][j] = (f32x4v){0.f, 0.f, 0.f, 0.f};

  // staging source seg, swizzled per destination row (row bits 0-3 only)
  const int srow = tid >> 2;
  const int sseg0 = (tid & 3) ^ bsw(srow);

  for (int k0 = 0; k0 < K; k0 += 32) {
#pragma unroll
    for (int i = 0; i < 2; ++i) {
      const int row = srow + i * 64;
      gl_lds16(A + (m0 + row) * (long)K + k0 + sseg0 * 8, As + (i * 256 + wave * 64) * 8);
      gl_lds16(B + (n0 + row) * (long)K + k0 + sseg0 * 8, Bs + (i * 256 + wave * 64) * 8);
    }
    __syncthreads();
    bf16x8 af[4], bfr[4];
#pragma unroll
    for (int mi = 0; mi < 4; ++mi)
      af[mi] = *(const bf16x8*)(As + (wr * 64 + mi * 16 + fr) * 32 + fs * 8);
#pragma unroll
    for (int ni = 0; ni < 4; ++ni)
      bfr[ni] = *(const bf16x8*)(Bs + (wc * 64 + ni * 16 + fr) * 32 + fs * 8);
#pragma unroll
    for (int mi = 0; mi < 4; ++mi)
#pragma unroll
      for (int ni = 0; ni < 4; ++ni)
        acc[mi][ni] = __builtin_amdgcn_mfma_f32_16x16x32_bf16(af[mi], bfr[ni], acc[mi][ni], 0, 0, 0);
    __syncthreads();
  }

#pragma unroll
  for (int mi = 0; mi < 4; ++mi) {
#pragma unroll
    for (int ni = 0; ni < 4; ++ni) {
      const long col = n0 + wc * 64 + ni * 16 + fr;
#pragma unroll
      for (int r = 0; r < 4; ++r) {
        const long rowi = m0 + wr * 64 + mi * 16 + fq * 4 + r;
        if constexpr (MODE == 0) {
          ((float*)Cp)[rowi * N + col] = acc[mi][ni][r];
        } else {
          const float z = acc[mi][ni][r] + bias[col];
          const float dtv = (z > 20.f) ? z : log1pf(__expf(z));
          ((float*)Cp)[col * (long)M + rowi] = dtv;  // transposed [N][M]
        }
      }
    }
  }
}

// ---------------- 256x256 8-wave phase-split GEMM (T1+T2+T3+T4+T5) -------------
// C[m][n] = sum_k A[m][k]*B[n][k]; M%256==0, N%256==0, K%64==0. grid.x % 8 == 0.
// 8 waves as 2(m) x 4(n); per-wave output 128x64; BK=32; LDS 64KB double-buffered.
// Counted vmcnt(4): next tile's 4 loads stay in flight across barriers.
// T2: linear LDS dest + XOR-swizzled global source seg + XOR-swizzled read seg.
template<int OUTBF>
__global__ __launch_bounds__(512, 2) void gemm256(
    const u16* __restrict__ A, const u16* __restrict__ B, void* __restrict__ Cp,
    int M, int N, int K)
{
  __shared__ __align__(16) u16 lds[2][2][8192];  // [buf][A=0/B=1][256 rows][32 k]
  const int tid = threadIdx.x;
  const int lane = tid & 63;
  const int wid = tid >> 6;
  const int wm = wid >> 2;   // 0..1
  const int wn = wid & 3;    // 0..3
  const int fr = lane & 15;
  const int fq = lane >> 4;
  const int fs = fq ^ bsw(fr);   // swizzled k-seg for fragment reads

  // XCD-aware swizzle: blocks resident on one XCD get consecutive logical tiles
  const int nbx = N >> 8;
  const int cpx = gridDim.x >> 3;
  const int bid = blockIdx.x;
  const int swz = (bid & 7) * cpx + (bid >> 3);
  const long m0 = (long)(swz / nbx) << 8;
  const long n0 = (long)(swz % nbx) << 8;

  // staging: 512 threads x 16B covers 8KB; each operand-tile (16KB) = 2 issues
  const int srow = tid >> 2;                     // 0..127 (+128 for second half)
  const int sseg = (tid & 3) ^ bsw(srow);        // T2 source swizzle
  const u16* ag0 = A + (m0 + srow) * (long)K + sseg * 8;
  const u16* ag1 = ag0 + 128 * (long)K;
  const u16* bg0 = B + (n0 + srow) * (long)K + sseg * 8;
  const u16* bg1 = bg0 + 128 * (long)K;

  auto stage = [&](int c, int koff) {
    gl_lds16(ag0 + koff, &lds[c][0][tid * 8]);
    gl_lds16(ag1 + koff, &lds[c][0][4096 + tid * 8]);
    gl_lds16(bg0 + koff, &lds[c][1][tid * 8]);
    gl_lds16(bg1 + koff, &lds[c][1][4096 + tid * 8]);
  };

  const int NT = K >> 5;
  stage(0, 0);
  stage(1, 32);
  asm volatile("s_waitcnt vmcnt(4)" ::: "memory");  // tile0 landed (own loads)
  __builtin_amdgcn_s_barrier();                     // -> landed for all waves

  f32x4v acc[8][4];
#pragma unroll
  for (int i = 0; i < 8; ++i)
#pragma unroll
    for (int j = 0; j < 4; ++j) acc[i][j] = (f32x4v){0.f, 0.f, 0.f, 0.f};

  const int aoff = (wm * 128 + fr) * 32 + fs * 8;  // +mi*512 per m-rep
  const int boff = (wn * 64 + fr) * 32 + fs * 8;   // +ni*512 per n-rep
  bf16x8 af[4], bfg[4];

  for (int t = 0; t < NT; ++t) {
    const int c = t & 1;
    const u16* Asl = &lds[c][0][0];
    const u16* Bsl = &lds[c][1][0];
    // ---- phase 0: frags m0-3 + all B; MFMA upper half ----
#pragma unroll
    for (int mi = 0; mi < 4; ++mi) af[mi] = *(const bf16x8*)(Asl + aoff + mi * 512);
#pragma unroll
    for (int ni = 0; ni < 4; ++ni) bfg[ni] = *(const bf16x8*)(Bsl + boff + ni * 512);
    __builtin_amdgcn_s_barrier();
    asm volatile("s_waitcnt lgkmcnt(0)" ::: "memory");
    __builtin_amdgcn_s_setprio(1);
#pragma unroll
    for (int mi = 0; mi < 4; ++mi)
#pragma unroll
      for (int ni = 0; ni < 4; ++ni)
        acc[mi][ni] = __builtin_amdgcn_mfma_f32_16x16x32_bf16(af[mi], bfg[ni], acc[mi][ni], 0, 0, 0);
    __builtin_amdgcn_s_setprio(0);
    __builtin_amdgcn_s_barrier();
    // ---- phase 1: frags m4-7; stage tile t+2 into buf c; MFMA lower half ----
#pragma unroll
    for (int mi = 0; mi < 4; ++mi) af[mi] = *(const bf16x8*)(Asl + aoff + 2048 + mi * 512);
    asm volatile("s_waitcnt lgkmcnt(0)" ::: "memory");  // this wave's reads of buf c done
    __builtin_amdgcn_s_barrier();                       // ALL waves' reads done -> buf c reusable
    if (t + 2 < NT) stage(c, (t + 2) * 32);
    __builtin_amdgcn_s_setprio(1);
#pragma unroll
    for (int mi = 0; mi < 4; ++mi)
#pragma unroll
      for (int ni = 0; ni < 4; ++ni)
        acc[mi + 4][ni] = __builtin_amdgcn_mfma_f32_16x16x32_bf16(af[mi], bfg[ni], acc[mi + 4][ni], 0, 0, 0);
    __builtin_amdgcn_s_setprio(0);
    if (t + 2 < NT) {
      asm volatile("s_waitcnt vmcnt(4)" ::: "memory");  // tile t+1 landed; t+2 in flight
    } else {
      asm volatile("s_waitcnt vmcnt(0)" ::: "memory");  // drain tail
    }
    __builtin_amdgcn_s_barrier();
  }

#pragma unroll
  for (int mi = 0; mi < 8; ++mi) {
#pragma unroll
    for (int ni = 0; ni < 4; ++ni) {
      const long col = n0 + wn * 64 + ni * 16 + fr;
      const long rbase = m0 + wm * 128 + mi * 16 + fq * 4;
#pragma unroll
      for (int r = 0; r < 4; ++r) {
        if constexpr (OUTBF) {
          ((u16*)Cp)[(rbase + r) * N + col] = f2b(acc[mi][ni][r]);
        } else {
          ((float*)Cp)[(rbase + r) * N + col] = acc[mi][ni][r];
        }
      }
    }
  }
}

// ---------------- causal depthwise conv (K=4) + SiLU, proj(bf16) -> x(bf16) ------
__global__ __launch_bounds__(256) void conv_silu_kernel(
    const u16* __restrict__ proj, const float* __restrict__ conv_w,
    const float* __restrict__ conv_b, u16* __restrict__ xb)
{
  const int idx = blockIdx.x * 256 + threadIdx.x;
  const int tok = idx >> 11;
  const int dq = (idx & 2047) << 2;
  const int l = tok & (LSEQ - 1);
  f32x4v cb = *(const f32x4v*)(conv_b + dq);
  float a0 = cb[0], a1 = cb[1], a2 = cb[2], a3 = cb[3];
  f32x4v w0 = *(const f32x4v*)(conv_w + (size_t)(dq + 0) * 4);
  f32x4v w1 = *(const f32x4v*)(conv_w + (size_t)(dq + 1) * 4);
  f32x4v w2 = *(const f32x4v*)(conv_w + (size_t)(dq + 2) * 4);
  f32x4v w3 = *(const f32x4v*)(conv_w + (size_t)(dq + 3) * 4);
#pragma unroll
  for (int j = 0; j < 4; ++j) {
    const int lj = l - 3 + j;
    if (lj >= 0) {
      ushort4 xv = *(const ushort4*)(proj + (size_t)(tok - 3 + j) * 16384 + dq);
      a0 = fmaf(w0[j], b2f(xv.x), a0);
      a1 = fmaf(w1[j], b2f(xv.y), a1);
      a2 = fmaf(w2[j], b2f(xv.z), a2);
      a3 = fmaf(w3[j], b2f(xv.w), a3);
    }
  }
  ushort4 o;
  o.x = f2b(a0 / (1.f + __expf(-a0)));
  o.y = f2b(a1 / (1.f + __expf(-a1)));
  o.z = f2b(a2 / (1.f + __expf(-a2)));
  o.w = f2b(a3 / (1.f + __expf(-a3)));
  *(ushort4*)(xb + (size_t)tok * DIN + dq) = o;
}

// ---------------- x [2048][8192] -> x_T [8192][2048] (4x4 register transpose) ----
__global__ __launch_bounds__(256) void transpose_x_kernel(
    const u16* __restrict__ in, u16* __restrict__ outp)
{
  const int t = threadIdx.x;
  const int sr = t >> 4, sc = t & 15;
  const long r0 = (long)blockIdx.x * 64 + sr * 4;
  const long c0 = (long)blockIdx.y * 64 + sc * 4;
  ushort4 v[4];
#pragma unroll
  for (int i = 0; i < 4; ++i)
    v[i] = *(const ushort4*)(in + (r0 + i) * DIN + c0);
#pragma unroll
  for (int i = 0; i < 4; ++i) {
    ushort4 o;
    o.x = ((const u16*)&v[0])[i];
    o.y = ((const u16*)&v[1])[i];
    o.z = ((const u16*)&v[2])[i];
    o.w = ((const u16*)&v[3])[i];
    *(ushort4*)(outp + (c0 + i) * BLT + r0) = o;
  }
}

// ---------------- RMS norm of ts(256), Bm(16), Cm(16) per token ----------------
__global__ __launch_bounds__(64) void rms_kernel(
    const float* __restrict__ ssm, u16* __restrict__ tsb,
    float* __restrict__ Bn, float* __restrict__ Cn)
{
  const int tok = blockIdx.x;
  const int lane = threadIdx.x;
  const float* row = ssm + (size_t)tok * 384;
  f32x4v t = *(const f32x4v*)(row + lane * 4);
  float ss = t[0]*t[0] + t[1]*t[1] + t[2]*t[2] + t[3]*t[3];
#pragma unroll
  for (int o = 32; o; o >>= 1) ss += __shfl_xor(ss, o);
  const float sc = rsqrtf(ss * (1.f / 256.f) + 1e-6f);
  ushort4 o4;
  o4.x = f2b(t[0] * sc); o4.y = f2b(t[1] * sc);
  o4.z = f2b(t[2] * sc); o4.w = f2b(t[3] * sc);
  *(ushort4*)(tsb + (size_t)tok * 256 + lane * 4) = o4;

  float v = 0.f;
  if (lane < 32) v = row[256 + lane];
  float g = v * v;
#pragma unroll
  for (int o = 1; o < 16; o <<= 1) g += __shfl_xor(g, o);
  const float scBC = rsqrtf(g * (1.f / 16.f) + 1e-6f);
  if (lane < 16) Bn[(size_t)tok * 16 + lane] = v * scBC;
  else if (lane < 32) Cn[(size_t)tok * 16 + (lane - 16)] = v * scBC;
}

// ---------------- chunked scan phase 1: per-chunk partials (E, S) ----------------
__global__ __launch_bounds__(256) void scan_p1_kernel(
    const float* __restrict__ dtT, const u16* __restrict__ xT,
    const float* __restrict__ Bn, const float* __restrict__ A_log,
    float* __restrict__ partE, float* __restrict__ partS)
{
  __shared__ float Bsh[CL][16];
  const int tid = threadIdx.x;
  const int chunk = blockIdx.y;
  const int d = blockIdx.x * 64 + (tid >> 2);
  const int ln = tid & 3;
  const int tok0 = chunk * CL;
  {
    const int tt = tid >> 2, q = tid & 3;
    *(f32x4v*)&Bsh[tt][q * 4] = *(const f32x4v*)(Bn + (size_t)(tok0 + tt) * 16 + q * 4);
  }
  __syncthreads();
  float a[4];
#pragma unroll
  for (int j = 0; j < 4; ++j) a[j] = -__expf(A_log[(size_t)d * 16 + ln * 4 + j]);
  float E0 = 1.f, E1 = 1.f, E2 = 1.f, E3 = 1.f;
  float S0 = 0.f, S1 = 0.f, S2 = 0.f, S3 = 0.f;
  const float* dtp = dtT + (size_t)d * BLT + tok0;
  const u16* xp = xT + (size_t)d * BLT + tok0;
  for (int l = 0; l < CL; l += 4) {
    f32x4v dt4 = *(const f32x4v*)(dtp + l);
    ushort4 u4 = *(const ushort4*)(xp + l);
#pragma unroll
    for (int i = 0; i < 4; ++i) {
      const float dt = dt4[i];
      const float u = b2f(((const u16*)&u4)[i]);
      const float dtu = dt * u;
      f32x4v Bv = *(const f32x4v*)&Bsh[l + i][ln * 4];
      const float e0 = __expf(dt * a[0]);
      const float e1 = __expf(dt * a[1]);
      const float e2 = __expf(dt * a[2]);
      const float e3 = __expf(dt * a[3]);
      S0 = fmaf(S0, e0, dtu * Bv[0]); E0 *= e0;
      S1 = fmaf(S1, e1, dtu * Bv[1]); E1 *= e1;
      S2 = fmaf(S2, e2, dtu * Bv[2]); E2 *= e2;
      S3 = fmaf(S3, e3, dtu * Bv[3]); E3 *= e3;
    }
  }
  const size_t off = (size_t)chunk * (DIN * 16) + (size_t)d * 16 + ln * 4;
  f32x4v Ev = {E0, E1, E2, E3}, Sv = {S0, S1, S2, S3};
  *(f32x4v*)(partE + off) = Ev;
  *(f32x4v*)(partS + off) = Sv;
}

// ---------------- chunked scan phase 2: combine chunk partials ----------------
__global__ __launch_bounds__(256) void scan_p2_kernel(
    const float* __restrict__ partE, float* __restrict__ partS)
{
  const int dn = blockIdx.x * 256 + threadIdx.x;
  float s = 0.f;
  for (int c = 0; c < NCG; ++c) {
    if ((c & 15) == 0) s = 0.f;  // batch boundary reset
    const size_t off = (size_t)c * (DIN * 16) + dn;
    const float e = partE[off];
    const float ps = partS[off];
    partS[off] = s;
    s = fmaf(e, s, ps);
  }
}

// ---------------- chunked scan phase 3: re-scan with true init, emit y ----------
__global__ __launch_bounds__(256) void scan_p3_kernel(
    const float* __restrict__ dtT, const u16* __restrict__ xT,
    const float* __restrict__ Bn, const float* __restrict__ Cn,
    const float* __restrict__ A_log, const float* __restrict__ Dv,
    const float* __restrict__ stateIn, const u16* __restrict__ proj,
    u16* __restrict__ yg)
{
  __shared__ float Bsh[CL][16], Csh[CL][16];
  const int tid = threadIdx.x;
  const int chunk = blockIdx.y;
  const int d = blockIdx.x * 64 + (tid >> 2);
  const int ln = tid & 3;
  const int tok0 = chunk * CL;
  {
    const int tt = tid >> 2, q = tid & 3;
    *(f32x4v*)&Bsh[tt][q * 4] = *(const f32x4v*)(Bn + (size_t)(tok0 + tt) * 16 + q * 4);
    *(f32x4v*)&Csh[tt][q * 4] = *(const f32x4v*)(Cn + (size_t)(tok0 + tt) * 16 + q * 4);
  }
  __syncthreads();
  float a[4];
#pragma unroll
  for (int j = 0; j < 4; ++j) a[j] = -__expf(A_log[(size_t)d * 16 + ln * 4 + j]);
  f32x4v sv = *(const f32x4v*)(stateIn + (size_t)chunk * (DIN * 16) + (size_t)d * 16 + ln * 4);
  float S0 = sv[0], S1 = sv[1], S2 = sv[2], S3 = sv[3];
  const float Dd = Dv[d];
  const float* dtp = dtT + (size_t)d * BLT + tok0;
  const u16* xp = xT + (size_t)d * BLT + tok0;
  for (int l = 0; l < CL; l += 4) {
    f32x4v dt4 = *(const f32x4v*)(dtp + l);
    ushort4 u4 = *(const ushort4*)(xp + l);
#pragma unroll
    for (int i = 0; i < 4; ++i) {
      const float dt = dt4[i];
      const float u = b2f(((const u16*)&u4)[i]);
      const float dtu = dt * u;
      f32x4v Bv = *(const f32x4v*)&Bsh[l + i][ln * 4];
      f32x4v Cv = *(const f32x4v*)&Csh[l + i][ln * 4];
      const float e0 = __expf(dt * a[0]);
      const float e1 = __expf(dt * a[1]);
      const float e2 = __expf(dt * a[2]);
      const float e3 = __expf(dt * a[3]);
      float y;
      S0 = fmaf(S0, e0, dtu * Bv[0]); y = S0 * Cv[0];
      S1 = fmaf(S1, e1, dtu * Bv[1]); y = fmaf(S1, Cv[1], y);
      S2 = fmaf(S2, e2, dtu * Bv[2]); y = fmaf(S2, Cv[2], y);
      S3 = fmaf(S3, e3, dtu * Bv[3]); y = fmaf(S3, Cv[3], y);
      y += __shfl_xor(y, 1);
      y += __shfl_xor(y, 2);
      if (ln == 0) {
        const long tok = tok0 + l + i;
        const float yt = fmaf(u, Dd, y);
        const float gt = b2f(proj[tok * 16384 + DIN + d]);
        const float sg = gt / (1.f + __expf(-gt));
        yg[tok * DIN + d] = f2b(yt * sg);
      }
    }
  }
}

extern "C" void kernel_launch(void* const* d_in, const int* in_sizes, int n_in,
                              void* d_out, int out_size, void* d_ws, size_t ws_size,
                              hipStream_t stream) {
  const float* hs     = (const float*)d_in[0];
  const float* W_in   = (const float*)d_in[1];
  const float* conv_w = (const float*)d_in[2];
  const float* conv_b = (const float*)d_in[3];
  const float* W_x    = (const float*)d_in[4];
  const float* W_dt   = (const float*)d_in[5];
  const float* b_dt   = (const float*)d_in[6];
  const float* A_log  = (const float*)d_in[7];
  const float* Dv     = (const float*)d_in[8];
  const float* W_out  = (const float*)d_in[9];
  float* out = (float*)d_out;

  char* ws = (char*)d_ws;
  size_t off = 0;
  auto alloc = [&](size_t bytes) -> char* {
    char* p = ws + off;
    off += (bytes + 255) & ~(size_t)255;
    return p;
  };

  u16* W_in_b = (u16*)alloc(134217728);                // R1: W_in_bf16 -> dt_T + W_out_b
  u16* hs_b = (u16*)alloc(16777216);                   // R2: hs_bf16 -> ssm/ts/Bn/Cn/W_dt
  u16* proj_b = (u16*)alloc((size_t)BLT * 16384 * 2);  // 67MB, lives to scan end (gate)
  u16* x_b    = (u16*)alloc((size_t)BLT * DIN * 2);    // 33.5MB; after GEMM5: partE+partS
  u16* W_xp_b = (u16*)alloc((size_t)384 * DIN * 2);    // 6.3MB
  u16* yg_b   = (u16*)alloc((size_t)BLT * DIN * 2);    // 33.5MB
  u16* x_T    = (u16*)alloc((size_t)BLT * DIN * 2);    // 33.5MB [DIN][BLT]

  float* dt_T   = (float*)W_in_b;
  u16*   W_out_b= (u16*)((char*)W_in_b + 67108864);
  float* ssm    = (float*)hs_b;
  u16*   ts_b   = (u16*)((char*)hs_b + 3145728);
  float* Bn     = (float*)((char*)hs_b + 3145728 + 1048576);
  float* Cn     = (float*)((char*)hs_b + 3145728 + 1048576 + 131072);
  u16*   W_dt_b = (u16*)((char*)hs_b + 3145728 + 1048576 + 262144);
  float* partE  = (float*)x_b;
  float* partS  = (float*)((char*)x_b + 16777216);

  const int CG = 2048;
  // 1) convert GEMM1 operands
  cvt_kernel<<<CG, 256, 0, stream>>>(W_in, W_in_b, 67108864L);
  cvt_kernel<<<CG, 256, 0, stream>>>(hs, hs_b, 8388608L);
  // 2) proj = hs @ W_in^T  (2048 x 16384, K=4096), bf16 out  [256^2 pipelined]
  gemm256<1><<<(16384 / 256) * (BLT / 256), 512, 0, stream>>>(hs_b, W_in_b, proj_b, BLT, 16384, 4096);
  // 3) convert remaining weights
  cvt_kernel<<<CG, 256, 0, stream>>>(W_out, W_out_b, 33554432L);
  cvt_kernel<<<CG, 256, 0, stream>>>(W_dt, W_dt_b, 2097152L);
  cvt_pad_kernel<<<CG, 256, 0, stream>>>(W_x, W_xp_b, 288, DIN, (long)384 * DIN);
  // 4) conv + silu -> x (bf16)
  conv_silu_kernel<<<16384, 256, 0, stream>>>(proj_b, conv_w, conv_b, x_b);
  // 5) x_T = transpose(x)  [DIN][BLT]
  transpose_x_kernel<<<dim3(BLT / 64, DIN / 64), 256, 0, stream>>>(x_b, x_T);
  // 6) ssm = x @ W_x^T (padded to 384 cols), f32 out
  gemm_bt<0><<<dim3(384 / 128, BLT / 128), 256, 0, stream>>>(x_b, W_xp_b, ssm, BLT, 384, DIN, nullptr);
  // 7) rms norms
  rms_kernel<<<BLT, 64, 0, stream>>>(ssm, ts_b, Bn, Cn);
  // 8) dt_T = softplus(ts_rms @ W_dt^T + b_dt), f32 TRANSPOSED [DIN][BLT]
  gemm_bt<2><<<dim3(DIN / 128, BLT / 128), 256, 0, stream>>>(ts_b, W_dt_b, dt_T, BLT, DIN, 256, b_dt);
  // 9) chunked scan
  scan_p1_kernel<<<dim3(DIN / 64, NCG), 256, 0, stream>>>(dt_T, x_T, Bn, A_log, partE, partS);
  scan_p2_kernel<<<DIN * 16 / 256, 256, 0, stream>>>(partE, partS);
  scan_p3_kernel<<<dim3(DIN / 64, NCG), 256, 0, stream>>>(dt_T, x_T, Bn, Cn, A_log, Dv, partS, proj_b, yg_b);
  // 10) out = ygated @ W_out^T (2048 x 4096, K=8192), f32 out  [256^2 pipelined]
  gemm256<0><<<(HH / 256) * (BLT / 256), 512, 0, stream>>>(yg_b, W_out_b, out, BLT, HH, DIN);
}

// Round 7
// 949.347 us; speedup vs baseline: 2.3993x; 1.2515x over previous
//
#include <hip/hip_runtime.h>
#include <hip/hip_bf16.h>

#define DIN 8192
#define HH 4096
#define BLT 2048   // total tokens (2*1024)
#define LSEQ 1024
#define CL 64      // scan chunk length
#define NCG 32     // total chunks (16 per batch)

typedef unsigned short u16;
typedef __bf16 bf16x8 __attribute__((ext_vector_type(8)));
typedef float f32x4v __attribute__((ext_vector_type(4)));

__device__ __forceinline__ u16 f2b(float f) {
  unsigned u = __float_as_uint(f);
  u += 0x7fff + ((u >> 16) & 1);
  return (u16)(u >> 16);
}
__device__ __forceinline__ float b2f(u16 h) {
  return __uint_as_float(((unsigned)h) << 16);
}

__device__ __forceinline__ void gl_lds16(const u16* g, u16* l) {
  __builtin_amdgcn_global_load_lds(
      (const __attribute__((address_space(1))) void*)g,
      (__attribute__((address_space(3))) void*)l, 16, 0, 0);
}

__device__ __forceinline__ int bsw(int r) { return (r & 3) ^ ((r >> 2) & 3); }

// ---------------- f32 -> bf16 convert (vectorized, grid-stride) ----------------
__global__ void cvt_kernel(const float* __restrict__ in, u16* __restrict__ out, long n) {
  long i = ((long)blockIdx.x * blockDim.x + threadIdx.x) * 4;
  long stride = (long)gridDim.x * blockDim.x * 4;
  for (; i < n; i += stride) {
    f32x4v v = *(const f32x4v*)(in + i);
    ushort4 o;
    o.x = f2b(v[0]); o.y = f2b(v[1]); o.z = f2b(v[2]); o.w = f2b(v[3]);
    *(ushort4*)(out + i) = o;
  }
}

// convert with row padding (W_x 288 rows -> 384 rows, pad rows = 0)
__global__ void cvt_pad_kernel(const float* __restrict__ in, u16* __restrict__ out,
                               int rows_in, int cols, long n_out) {
  long i = ((long)blockIdx.x * blockDim.x + threadIdx.x) * 4;
  long stride = (long)gridDim.x * blockDim.x * 4;
  for (; i < n_out; i += stride) {
    long r = i / cols;
    long c = i - r * cols;
    ushort4 o;
    if (r < rows_in) {
      f32x4v v = *(const f32x4v*)(in + r * cols + c);
      o.x = f2b(v[0]); o.y = f2b(v[1]); o.z = f2b(v[2]); o.w = f2b(v[3]);
    } else {
      o.x = 0; o.y = 0; o.z = 0; o.w = 0;
    }
    *(ushort4*)(out + i) = o;
  }
}

// ---- elementwise add of two f32 buffers (split-K reduce) ----
__global__ void add2_kernel(const float* __restrict__ a, const float* __restrict__ b,
                            float* __restrict__ o, long n) {
  long i = ((long)blockIdx.x * blockDim.x + threadIdx.x) * 4;
  long stride = (long)gridDim.x * blockDim.x * 4;
  for (; i < n; i += stride) {
    f32x4v va = *(const f32x4v*)(a + i);
    f32x4v vb = *(const f32x4v*)(b + i);
    *(f32x4v*)(o + i) = va + vb;
  }
}

// ---------------- m97-style 128x128 GEMM with split-K (blockIdx.z) -------------
// MODE 0: f32 out [z][M][N] (partial per K-slice).
// MODE 3: f32 out [M][N] with fused softplus(acc + bias[row]) (dt path, A=W_dt).
// A rows stride lda, B rows stride lda; k range = [z*Klen, (z+1)*Klen).
template<int MODE>
__global__ __launch_bounds__(256) void gemm_bt(
    const u16* __restrict__ A, const u16* __restrict__ B, void* __restrict__ Cp,
    int M, int N, int Klen, int lda, const float* __restrict__ bias = nullptr)
{
  __shared__ __align__(16) u16 As[128 * 32];
  __shared__ __align__(16) u16 Bs[128 * 32];
  const int tid = threadIdx.x;
  const int wave = tid >> 6;
  const int lane = tid & 63;
  const int wr = wave >> 1;
  const int wc = wave & 1;
  const long m0 = (long)blockIdx.y * 128;
  const long n0 = (long)blockIdx.x * 128;
  const long kbase = (long)blockIdx.z * Klen;
  const int fr = lane & 15;
  const int fq = lane >> 4;
  const int fs = fq ^ bsw(fr);

  f32x4v acc[4][4];
#pragma unroll
  for (int i = 0; i < 4; ++i)
#pragma unroll
    for (int j = 0; j < 4; ++j) acc[i][j] = (f32x4v){0.f, 0.f, 0.f, 0.f};

  const int srow = tid >> 2;
  const int sseg0 = (tid & 3) ^ bsw(srow);

  for (int k0 = 0; k0 < Klen; k0 += 32) {
#pragma unroll
    for (int i = 0; i < 2; ++i) {
      const int row = srow + i * 64;
      gl_lds16(A + (m0 + row) * (long)lda + kbase + k0 + sseg0 * 8, As + (i * 256 + wave * 64) * 8);
      gl_lds16(B + (n0 + row) * (long)lda + kbase + k0 + sseg0 * 8, Bs + (i * 256 + wave * 64) * 8);
    }
    __syncthreads();
    bf16x8 af[4], bfr[4];
#pragma unroll
    for (int mi = 0; mi < 4; ++mi)
      af[mi] = *(const bf16x8*)(As + (wr * 64 + mi * 16 + fr) * 32 + fs * 8);
#pragma unroll
    for (int ni = 0; ni < 4; ++ni)
      bfr[ni] = *(const bf16x8*)(Bs + (wc * 64 + ni * 16 + fr) * 32 + fs * 8);
#pragma unroll
    for (int mi = 0; mi < 4; ++mi)
#pragma unroll
      for (int ni = 0; ni < 4; ++ni)
        acc[mi][ni] = __builtin_amdgcn_mfma_f32_16x16x32_bf16(af[mi], bfr[ni], acc[mi][ni], 0, 0, 0);
    __syncthreads();
  }

  float* Cf = (float*)Cp + (size_t)blockIdx.z * M * N;
#pragma unroll
  for (int mi = 0; mi < 4; ++mi) {
#pragma unroll
    for (int ni = 0; ni < 4; ++ni) {
      const long col = n0 + wc * 64 + ni * 16 + fr;
#pragma unroll
      for (int r = 0; r < 4; ++r) {
        const long rowi = m0 + wr * 64 + mi * 16 + fq * 4 + r;
        if constexpr (MODE == 0) {
          Cf[rowi * N + col] = acc[mi][ni][r];
        } else {
          const float z = acc[mi][ni][r] + bias[rowi];
          const float dtv = (z > 20.f) ? z : log1pf(__expf(z));
          ((float*)Cp)[rowi * N + col] = dtv;   // [DIN][BLT], coalesced
        }
      }
    }
  }
}

// ---------------- 256x256 8-wave GEMM, 2 barriers/tile, counted waits ----------
// C[m][n] = sum_k A[m][k]*B[n][k]; A/B k-stride = Kfull; K-slice = blockIdx.y.
// OUTBF=1: bf16 out [M][N] (no split). OUTBF=0: f32 out [z][M][N] partials.
template<int OUTBF>
__global__ __launch_bounds__(512, 2) void gemm256(
    const u16* __restrict__ A, const u16* __restrict__ B, void* __restrict__ Cp,
    int M, int N, int Kfull, int Ksub)
{
  __shared__ __align__(16) u16 lds[2][2][8192];  // [buf][A=0/B=1][256 rows][32 k]
  const int tid = threadIdx.x;
  const int lane = tid & 63;
  const int wid = tid >> 6;
  const int wm = wid >> 2;
  const int wn = wid & 3;
  const int fr = lane & 15;
  const int fq = lane >> 4;
  const int fs = fq ^ bsw(fr);

  // XCD-aware swizzle over grid.x
  const int nbx = N >> 8;
  const int cpx = gridDim.x >> 3;
  const int bid = blockIdx.x;
  const int swz = (bid & 7) * cpx + (bid >> 3);
  const long m0 = (long)(swz / nbx) << 8;
  const long n0 = (long)(swz % nbx) << 8;
  const long kbase = (long)blockIdx.y * Ksub;

  const int srow = tid >> 2;
  const int sseg = (tid & 3) ^ bsw(srow);
  const u16* ag0 = A + (m0 + srow) * (long)Kfull + kbase + sseg * 8;
  const u16* ag1 = ag0 + 128 * (long)Kfull;
  const u16* bg0 = B + (n0 + srow) * (long)Kfull + kbase + sseg * 8;
  const u16* bg1 = bg0 + 128 * (long)Kfull;

  auto stage = [&](int c, int koff) {
    gl_lds16(ag0 + koff, &lds[c][0][tid * 8]);
    gl_lds16(ag1 + koff, &lds[c][0][4096 + tid * 8]);
    gl_lds16(bg0 + koff, &lds[c][1][tid * 8]);
    gl_lds16(bg1 + koff, &lds[c][1][4096 + tid * 8]);
  };

  const int NT = Ksub >> 5;
  stage(0, 0);
  stage(1, 32);
  asm volatile("s_waitcnt vmcnt(4)" ::: "memory");  // tile0 landed
  __builtin_amdgcn_s_barrier();

  f32x4v acc[8][4];
#pragma unroll
  for (int i = 0; i < 8; ++i)
#pragma unroll
    for (int j = 0; j < 4; ++j) acc[i][j] = (f32x4v){0.f, 0.f, 0.f, 0.f};

  const int aoff = (wm * 128 + fr) * 32 + fs * 8;
  const int boff = (wn * 64 + fr) * 32 + fs * 8;
  bf16x8 af[4], bfg[4], al[4];

  for (int t = 0; t < NT; ++t) {
    const int c = t & 1;
    const u16* Asl = &lds[c][0][0];
    const u16* Bsl = &lds[c][1][0];
    // issue all 12 ds_reads for this tile (A-upper, B, A-lower)
#pragma unroll
    for (int mi = 0; mi < 4; ++mi) af[mi] = *(const bf16x8*)(Asl + aoff + mi * 512);
#pragma unroll
    for (int ni = 0; ni < 4; ++ni) bfg[ni] = *(const bf16x8*)(Bsl + boff + ni * 512);
#pragma unroll
    for (int mi = 0; mi < 4; ++mi) al[mi] = *(const bf16x8*)(Asl + aoff + 2048 + mi * 512);
    asm volatile("s_waitcnt lgkmcnt(4)" ::: "memory");  // first 8 (af,bfg) done
    __builtin_amdgcn_sched_barrier(0);
    __builtin_amdgcn_s_setprio(1);
#pragma unroll
    for (int mi = 0; mi < 4; ++mi)
#pragma unroll
      for (int ni = 0; ni < 4; ++ni)
        acc[mi][ni] = __builtin_amdgcn_mfma_f32_16x16x32_bf16(af[mi], bfg[ni], acc[mi][ni], 0, 0, 0);
    __builtin_amdgcn_s_setprio(0);
    asm volatile("s_waitcnt lgkmcnt(0)" ::: "memory");  // al reads done (hid under MFMA)
    __builtin_amdgcn_sched_barrier(0);
    __builtin_amdgcn_s_barrier();                       // ALL waves done reading buf c
    if (t + 2 < NT) stage(c, (t + 2) * 32);             // overwrite buf c with tile t+2
    __builtin_amdgcn_s_setprio(1);
#pragma unroll
    for (int mi = 0; mi < 4; ++mi)
#pragma unroll
      for (int ni = 0; ni < 4; ++ni)
        acc[mi + 4][ni] = __builtin_amdgcn_mfma_f32_16x16x32_bf16(al[mi], bfg[ni], acc[mi + 4][ni], 0, 0, 0);
    __builtin_amdgcn_s_setprio(0);
    if (t + 2 < NT) {
      asm volatile("s_waitcnt vmcnt(4)" ::: "memory");  // tile t+1 landed; t+2 in flight
    } else {
      asm volatile("s_waitcnt vmcnt(0)" ::: "memory");  // drain tail
    }
    __builtin_amdgcn_s_barrier();                       // buf for next tile ready
  }

  float* Cf = (float*)Cp + (size_t)blockIdx.y * M * N;
#pragma unroll
  for (int mi = 0; mi < 8; ++mi) {
#pragma unroll
    for (int ni = 0; ni < 4; ++ni) {
      const long col = n0 + wn * 64 + ni * 16 + fr;
      const long rbase = m0 + wm * 128 + mi * 16 + fq * 4;
#pragma unroll
      for (int r = 0; r < 4; ++r) {
        if constexpr (OUTBF) {
          ((u16*)Cp)[(rbase + r) * N + col] = f2b(acc[mi][ni][r]);
        } else {
          Cf[(rbase + r) * N + col] = acc[mi][ni][r];
        }
      }
    }
  }
}

// ---------------- causal depthwise conv (K=4) + SiLU, proj(bf16) -> x(bf16) ------
__global__ __launch_bounds__(256) void conv_silu_kernel(
    const u16* __restrict__ proj, const float* __restrict__ conv_w,
    const float* __restrict__ conv_b, u16* __restrict__ xb)
{
  const int idx = blockIdx.x * 256 + threadIdx.x;
  const int tok = idx >> 11;
  const int dq = (idx & 2047) << 2;
  const int l = tok & (LSEQ - 1);
  f32x4v cb = *(const f32x4v*)(conv_b + dq);
  float a0 = cb[0], a1 = cb[1], a2 = cb[2], a3 = cb[3];
  f32x4v w0 = *(const f32x4v*)(conv_w + (size_t)(dq + 0) * 4);
  f32x4v w1 = *(const f32x4v*)(conv_w + (size_t)(dq + 1) * 4);
  f32x4v w2 = *(const f32x4v*)(conv_w + (size_t)(dq + 2) * 4);
  f32x4v w3 = *(const f32x4v*)(conv_w + (size_t)(dq + 3) * 4);
#pragma unroll
  for (int j = 0; j < 4; ++j) {
    const int lj = l - 3 + j;
    if (lj >= 0) {
      ushort4 xv = *(const ushort4*)(proj + (size_t)(tok - 3 + j) * 16384 + dq);
      a0 = fmaf(w0[j], b2f(xv.x), a0);
      a1 = fmaf(w1[j], b2f(xv.y), a1);
      a2 = fmaf(w2[j], b2f(xv.z), a2);
      a3 = fmaf(w3[j], b2f(xv.w), a3);
    }
  }
  ushort4 o;
  o.x = f2b(a0 / (1.f + __expf(-a0)));
  o.y = f2b(a1 / (1.f + __expf(-a1)));
  o.z = f2b(a2 / (1.f + __expf(-a2)));
  o.w = f2b(a3 / (1.f + __expf(-a3)));
  *(ushort4*)(xb + (size_t)tok * DIN + dq) = o;
}

// ---------------- x [2048][8192] -> x_T [8192][2048] (4x4 register transpose) ----
__global__ __launch_bounds__(256) void transpose_x_kernel(
    const u16* __restrict__ in, u16* __restrict__ outp)
{
  const int t = threadIdx.x;
  const int sr = t >> 4, sc = t & 15;
  const long r0 = (long)blockIdx.x * 64 + sr * 4;
  const long c0 = (long)blockIdx.y * 64 + sc * 4;
  ushort4 v[4];
#pragma unroll
  for (int i = 0; i < 4; ++i)
    v[i] = *(const ushort4*)(in + (r0 + i) * DIN + c0);
#pragma unroll
  for (int i = 0; i < 4; ++i) {
    ushort4 o;
    o.x = ((const u16*)&v[0])[i];
    o.y = ((const u16*)&v[1])[i];
    o.z = ((const u16*)&v[2])[i];
    o.w = ((const u16*)&v[3])[i];
    *(ushort4*)(outp + (c0 + i) * BLT + r0) = o;
  }
}

// ---------------- RMS norms; input = 8 split-K partials of ssm ----------------
__global__ __launch_bounds__(64) void rms_kernel(
    const float* __restrict__ part, u16* __restrict__ tsb,
    float* __restrict__ Bn, float* __restrict__ Cn)
{
  const int tok = blockIdx.x;
  const int lane = threadIdx.x;
  const size_t rowoff = (size_t)tok * 384;
  f32x4v t = (f32x4v){0.f, 0.f, 0.f, 0.f};
#pragma unroll
  for (int s = 0; s < 8; ++s)
    t += *(const f32x4v*)(part + (size_t)s * (BLT * 384) + rowoff + lane * 4);
  float ss = t[0]*t[0] + t[1]*t[1] + t[2]*t[2] + t[3]*t[3];
#pragma unroll
  for (int o = 32; o; o >>= 1) ss += __shfl_xor(ss, o);
  const float sc = rsqrtf(ss * (1.f / 256.f) + 1e-6f);
  ushort4 o4;
  o4.x = f2b(t[0] * sc); o4.y = f2b(t[1] * sc);
  o4.z = f2b(t[2] * sc); o4.w = f2b(t[3] * sc);
  *(ushort4*)(tsb + (size_t)tok * 256 + lane * 4) = o4;

  float v = 0.f;
  if (lane < 32) {
#pragma unroll
    for (int s = 0; s < 8; ++s)
      v += part[(size_t)s * (BLT * 384) + rowoff + 256 + lane];
  }
  float g = v * v;
#pragma unroll
  for (int o = 1; o < 16; o <<= 1) g += __shfl_xor(g, o);
  const float scBC = rsqrtf(g * (1.f / 16.f) + 1e-6f);
  if (lane < 16) Bn[(size_t)tok * 16 + lane] = v * scBC;
  else if (lane < 32) Cn[(size_t)tok * 16 + (lane - 16)] = v * scBC;
}

// ---------------- chunked scan phase 1: per-chunk partials (E, S) ----------------
__global__ __launch_bounds__(256) void scan_p1_kernel(
    const float* __restrict__ dtT, const u16* __restrict__ xT,
    const float* __restrict__ Bn, const float* __restrict__ A_log,
    float* __restrict__ partE, float* __restrict__ partS)
{
  __shared__ float Bsh[CL][16];
  const int tid = threadIdx.x;
  const int chunk = blockIdx.y;
  const int d = blockIdx.x * 64 + (tid >> 2);
  const int ln = tid & 3;
  const int tok0 = chunk * CL;
  {
    const int tt = tid >> 2, q = tid & 3;
    *(f32x4v*)&Bsh[tt][q * 4] = *(const f32x4v*)(Bn + (size_t)(tok0 + tt) * 16 + q * 4);
  }
  __syncthreads();
  float a[4];
#pragma unroll
  for (int j = 0; j < 4; ++j) a[j] = -__expf(A_log[(size_t)d * 16 + ln * 4 + j]);
  float E0 = 1.f, E1 = 1.f, E2 = 1.f, E3 = 1.f;
  float S0 = 0.f, S1 = 0.f, S2 = 0.f, S3 = 0.f;
  const float* dtp = dtT + (size_t)d * BLT + tok0;
  const u16* xp = xT + (size_t)d * BLT + tok0;
  for (int l = 0; l < CL; l += 4) {
    f32x4v dt4 = *(const f32x4v*)(dtp + l);
    ushort4 u4 = *(const ushort4*)(xp + l);
#pragma unroll
    for (int i = 0; i < 4; ++i) {
      const float dt = dt4[i];
      const float u = b2f(((const u16*)&u4)[i]);
      const float dtu = dt * u;
      f32x4v Bv = *(const f32x4v*)&Bsh[l + i][ln * 4];
      const float e0 = __expf(dt * a[0]);
      const float e1 = __expf(dt * a[1]);
      const float e2 = __expf(dt * a[2]);
      const float e3 = __expf(dt * a[3]);
      S0 = fmaf(S0, e0, dtu * Bv[0]); E0 *= e0;
      S1 = fmaf(S1, e1, dtu * Bv[1]); E1 *= e1;
      S2 = fmaf(S2, e2, dtu * Bv[2]); E2 *= e2;
      S3 = fmaf(S3, e3, dtu * Bv[3]); E3 *= e3;
    }
  }
  const size_t off = (size_t)chunk * (DIN * 16) + (size_t)d * 16 + ln * 4;
  f32x4v Ev = {E0, E1, E2, E3}, Sv = {S0, S1, S2, S3};
  *(f32x4v*)(partE + off) = Ev;
  *(f32x4v*)(partS + off) = Sv;
}

// ---------------- chunked scan phase 2: combine chunk partials ----------------
__global__ __launch_bounds__(256) void scan_p2_kernel(
    const float* __restrict__ partE, float* __restrict__ partS)
{
  const int dn = blockIdx.x * 256 + threadIdx.x;
  float s = 0.f;
  for (int c = 0; c < NCG; ++c) {
    if ((c & 15) == 0) s = 0.f;  // batch boundary reset
    const size_t off = (size_t)c * (DIN * 16) + dn;
    const float e = partE[off];
    const float ps = partS[off];
    partS[off] = s;
    s = fmaf(e, s, ps);
  }
}

// ---------------- chunked scan phase 3: re-scan with true init, emit y ----------
__global__ __launch_bounds__(256) void scan_p3_kernel(
    const float* __restrict__ dtT, const u16* __restrict__ xT,
    const float* __restrict__ Bn, const float* __restrict__ Cn,
    const float* __restrict__ A_log, const float* __restrict__ Dv,
    const float* __restrict__ stateIn, const u16* __restrict__ proj,
    u16* __restrict__ yg)
{
  __shared__ float Bsh[CL][16], Csh[CL][16];
  const int tid = threadIdx.x;
  const int chunk = blockIdx.y;
  const int d = blockIdx.x * 64 + (tid >> 2);
  const int ln = tid & 3;
  const int tok0 = chunk * CL;
  {
    const int tt = tid >> 2, q = tid & 3;
    *(f32x4v*)&Bsh[tt][q * 4] = *(const f32x4v*)(Bn + (size_t)(tok0 + tt) * 16 + q * 4);
    *(f32x4v*)&Csh[tt][q * 4] = *(const f32x4v*)(Cn + (size_t)(tok0 + tt) * 16 + q * 4);
  }
  __syncthreads();
  float a[4];
#pragma unroll
  for (int j = 0; j < 4; ++j) a[j] = -__expf(A_log[(size_t)d * 16 + ln * 4 + j]);
  f32x4v sv = *(const f32x4v*)(stateIn + (size_t)chunk * (DIN * 16) + (size_t)d * 16 + ln * 4);
  float S0 = sv[0], S1 = sv[1], S2 = sv[2], S3 = sv[3];
  const float Dd = Dv[d];
  const float* dtp = dtT + (size_t)d * BLT + tok0;
  const u16* xp = xT + (size_t)d * BLT + tok0;
  for (int l = 0; l < CL; l += 4) {
    f32x4v dt4 = *(const f32x4v*)(dtp + l);
    ushort4 u4 = *(const ushort4*)(xp + l);
#pragma unroll
    for (int i = 0; i < 4; ++i) {
      const float dt = dt4[i];
      const float u = b2f(((const u16*)&u4)[i]);
      const float dtu = dt * u;
      f32x4v Bv = *(const f32x4v*)&Bsh[l + i][ln * 4];
      f32x4v Cv = *(const f32x4v*)&Csh[l + i][ln * 4];
      const float e0 = __expf(dt * a[0]);
      const float e1 = __expf(dt * a[1]);
      const float e2 = __expf(dt * a[2]);
      const float e3 = __expf(dt * a[3]);
      float y;
      S0 = fmaf(S0, e0, dtu * Bv[0]); y = S0 * Cv[0];
      S1 = fmaf(S1, e1, dtu * Bv[1]); y = fmaf(S1, Cv[1], y);
      S2 = fmaf(S2, e2, dtu * Bv[2]); y = fmaf(S2, Cv[2], y);
      S3 = fmaf(S3, e3, dtu * Bv[3]); y = fmaf(S3, Cv[3], y);
      y += __shfl_xor(y, 1);
      y += __shfl_xor(y, 2);
      if (ln == 0) {
        const long tok = tok0 + l + i;
        const float yt = fmaf(u, Dd, y);
        const float gt = b2f(proj[tok * 16384 + DIN + d]);
        const float sg = gt / (1.f + __expf(-gt));
        yg[tok * DIN + d] = f2b(yt * sg);
      }
    }
  }
}

extern "C" void kernel_launch(void* const* d_in, const int* in_sizes, int n_in,
                              void* d_out, int out_size, void* d_ws, size_t ws_size,
                              hipStream_t stream) {
  const float* hs     = (const float*)d_in[0];
  const float* W_in   = (const float*)d_in[1];
  const float* conv_w = (const float*)d_in[2];
  const float* conv_b = (const float*)d_in[3];
  const float* W_x    = (const float*)d_in[4];
  const float* W_dt   = (const float*)d_in[5];
  const float* b_dt   = (const float*)d_in[6];
  const float* A_log  = (const float*)d_in[7];
  const float* Dv     = (const float*)d_in[8];
  const float* W_out  = (const float*)d_in[9];
  float* out = (float*)d_out;

  char* ws = (char*)d_ws;
  size_t off = 0;
  auto alloc = [&](size_t bytes) -> char* {
    char* p = ws + off;
    off += (bytes + 255) & ~(size_t)255;
    return p;
  };

  u16* W_in_b = (u16*)alloc(134217728);                // R1: W_in_bf16 -> dt_T + W_out_b
  u16* hs_b = (u16*)alloc(16777216);                   // R2: hs_bf16 -> ts/Bn/Cn/W_dt
  u16* proj_b = (u16*)alloc((size_t)BLT * 16384 * 2);  // 67MB; after scan: out_part[2]
  u16* x_b    = (u16*)alloc((size_t)BLT * DIN * 2);    // 33.5MB; after ssm: partE+partS
  u16* W_xp_b = (u16*)alloc((size_t)384 * DIN * 2);    // 6.3MB
  u16* yg_b   = (u16*)alloc((size_t)BLT * DIN * 2);    // 33.5MB; pre-scan: ssm_part[8]
  u16* x_T    = (u16*)alloc((size_t)BLT * DIN * 2);    // 33.5MB [DIN][BLT]

  float* dt_T    = (float*)W_in_b;                     // [DIN][BLT] f32, 67MB
  u16*   W_out_b = (u16*)((char*)W_in_b + 67108864);
  u16*   ts_b    = (u16*)((char*)hs_b + 3145728);
  float* Bn      = (float*)((char*)hs_b + 3145728 + 1048576);
  float* Cn      = (float*)((char*)hs_b + 3145728 + 1048576 + 131072);
  u16*   W_dt_b  = (u16*)((char*)hs_b + 3145728 + 1048576 + 262144);
  float* partE   = (float*)x_b;
  float* partS   = (float*)((char*)x_b + 16777216);
  float* ssm_part= (float*)yg_b;                       // [8][2048][384] = 25.2MB
  float* out_part= (float*)proj_b;                     // [2][2048][4096] = 67MB

  const int CG = 2048;
  // 1) convert GEMM1 operands
  cvt_kernel<<<CG, 256, 0, stream>>>(W_in, W_in_b, 67108864L);
  cvt_kernel<<<CG, 256, 0, stream>>>(hs, hs_b, 8388608L);
  // 2) proj = hs @ W_in^T  (2048 x 16384, K=4096), bf16 out
  gemm256<1><<<dim3((16384 / 256) * (BLT / 256), 1), 512, 0, stream>>>(hs_b, W_in_b, proj_b, BLT, 16384, 4096, 4096);
  // 3) convert remaining weights
  cvt_kernel<<<CG, 256, 0, stream>>>(W_out, W_out_b, 33554432L);
  cvt_kernel<<<CG, 256, 0, stream>>>(W_dt, W_dt_b, 2097152L);
  cvt_pad_kernel<<<CG, 256, 0, stream>>>(W_x, W_xp_b, 288, DIN, (long)384 * DIN);
  // 4) conv + silu -> x (bf16)
  conv_silu_kernel<<<16384, 256, 0, stream>>>(proj_b, conv_w, conv_b, x_b);
  // 5) x_T = transpose(x)  [DIN][BLT]
  transpose_x_kernel<<<dim3(BLT / 64, DIN / 64), 256, 0, stream>>>(x_b, x_T);
  // 6) ssm partials: x @ W_x^T split-K=8 (Klen=1024), f32 partials in ssm_part
  gemm_bt<0><<<dim3(384 / 128, BLT / 128, 8), 256, 0, stream>>>(x_b, W_xp_b, ssm_part, BLT, 384, 1024, DIN, nullptr);
  // 7) rms norms (reduces the 8 partials)
  rms_kernel<<<BLT, 64, 0, stream>>>(ssm_part, ts_b, Bn, Cn);
  // 8) dt_T[d][tok] = softplus(W_dt @ ts^T + b_dt[d]) — A=W_dt (M=8192), coalesced
  gemm_bt<3><<<dim3(BLT / 128, DIN / 128), 256, 0, stream>>>(W_dt_b, ts_b, dt_T, DIN, BLT, 256, 256, b_dt);
  // 9) chunked scan
  scan_p1_kernel<<<dim3(DIN / 64, NCG), 256, 0, stream>>>(dt_T, x_T, Bn, A_log, partE, partS);
  scan_p2_kernel<<<DIN * 16 / 256, 256, 0, stream>>>(partE, partS);
  scan_p3_kernel<<<dim3(DIN / 64, NCG), 256, 0, stream>>>(dt_T, x_T, Bn, Cn, A_log, Dv, partS, proj_b, yg_b);
  // 10) out = ygated @ W_out^T split-K=2 (256 blocks), f32 partials then add
  gemm256<0><<<dim3((HH / 256) * (BLT / 256), 2), 512, 0, stream>>>(yg_b, W_out_b, out_part, BLT, HH, DIN, DIN / 2);
  add2_kernel<<<CG, 256, 0, stream>>>(out_part, out_part + (size_t)BLT * HH, out, (long)BLT * HH);
}

// Round 8
// 941.844 us; speedup vs baseline: 2.4184x; 1.0080x over previous
//
#include <hip/hip_runtime.h>
#include <hip/hip_bf16.h>

#define DIN 8192
#define HH 4096
#define BLT 2048   // total tokens (2*1024)
#define LSEQ 1024
#define CL 64      // scan chunk length
#define NCG 32     // total chunks (16 per batch)

typedef unsigned short u16;
typedef __bf16 bf16x8 __attribute__((ext_vector_type(8)));
typedef float f32x4v __attribute__((ext_vector_type(4)));

__device__ __forceinline__ u16 f2b(float f) {
  unsigned u = __float_as_uint(f);
  u += 0x7fff + ((u >> 16) & 1);
  return (u16)(u >> 16);
}
__device__ __forceinline__ float b2f(u16 h) {
  return __uint_as_float(((unsigned)h) << 16);
}

__device__ __forceinline__ void gl_lds16(const u16* g, u16* l) {
  __builtin_amdgcn_global_load_lds(
      (const __attribute__((address_space(1))) void*)g,
      (__attribute__((address_space(3))) void*)l, 16, 0, 0);
}

__device__ __forceinline__ int bsw(int r) { return (r & 3) ^ ((r >> 2) & 3); }

// ---------------- f32 -> bf16 convert (vectorized, grid-stride) ----------------
__global__ void cvt_kernel(const float* __restrict__ in, u16* __restrict__ out, long n) {
  long i = ((long)blockIdx.x * blockDim.x + threadIdx.x) * 4;
  long stride = (long)gridDim.x * blockDim.x * 4;
  for (; i < n; i += stride) {
    f32x4v v = *(const f32x4v*)(in + i);
    ushort4 o;
    o.x = f2b(v[0]); o.y = f2b(v[1]); o.z = f2b(v[2]); o.w = f2b(v[3]);
    *(ushort4*)(out + i) = o;
  }
}

// convert with row padding (W_x 288 rows -> 384 rows, pad rows = 0)
__global__ void cvt_pad_kernel(const float* __restrict__ in, u16* __restrict__ out,
                               int rows_in, int cols, long n_out) {
  long i = ((long)blockIdx.x * blockDim.x + threadIdx.x) * 4;
  long stride = (long)gridDim.x * blockDim.x * 4;
  for (; i < n_out; i += stride) {
    long r = i / cols;
    long c = i - r * cols;
    ushort4 o;
    if (r < rows_in) {
      f32x4v v = *(const f32x4v*)(in + r * cols + c);
      o.x = f2b(v[0]); o.y = f2b(v[1]); o.z = f2b(v[2]); o.w = f2b(v[3]);
    } else {
      o.x = 0; o.y = 0; o.z = 0; o.w = 0;
    }
    *(ushort4*)(out + i) = o;
  }
}

// ---- elementwise add of two f32 buffers (split-K reduce) ----
__global__ void add2_kernel(const float* __restrict__ a, const float* __restrict__ b,
                            float* __restrict__ o, long n) {
  long i = ((long)blockIdx.x * blockDim.x + threadIdx.x) * 4;
  long stride = (long)gridDim.x * blockDim.x * 4;
  for (; i < n; i += stride) {
    f32x4v va = *(const f32x4v*)(a + i);
    f32x4v vb = *(const f32x4v*)(b + i);
    *(f32x4v*)(o + i) = va + vb;
  }
}

// ---------------- m97-style 128x128 GEMM with split-K (blockIdx.z) -------------
// MODE 0: f32 out [z][M][N] (partial per K-slice).
// MODE 3: f32 out [M][N] with fused softplus(acc + bias[row]) (dt path, A=W_dt).
template<int MODE>
__global__ __launch_bounds__(256) void gemm_bt(
    const u16* __restrict__ A, const u16* __restrict__ B, void* __restrict__ Cp,
    int M, int N, int Klen, int lda, const float* __restrict__ bias = nullptr)
{
  __shared__ __align__(16) u16 As[128 * 32];
  __shared__ __align__(16) u16 Bs[128 * 32];
  const int tid = threadIdx.x;
  const int wave = tid >> 6;
  const int lane = tid & 63;
  const int wr = wave >> 1;
  const int wc = wave & 1;
  const long m0 = (long)blockIdx.y * 128;
  const long n0 = (long)blockIdx.x * 128;
  const long kbase = (long)blockIdx.z * Klen;
  const int fr = lane & 15;
  const int fq = lane >> 4;
  const int fs = fq ^ bsw(fr);

  f32x4v acc[4][4];
#pragma unroll
  for (int i = 0; i < 4; ++i)
#pragma unroll
    for (int j = 0; j < 4; ++j) acc[i][j] = (f32x4v){0.f, 0.f, 0.f, 0.f};

  const int srow = tid >> 2;
  const int sseg0 = (tid & 3) ^ bsw(srow);

  for (int k0 = 0; k0 < Klen; k0 += 32) {
#pragma unroll
    for (int i = 0; i < 2; ++i) {
      const int row = srow + i * 64;
      gl_lds16(A + (m0 + row) * (long)lda + kbase + k0 + sseg0 * 8, As + (i * 256 + wave * 64) * 8);
      gl_lds16(B + (n0 + row) * (long)lda + kbase + k0 + sseg0 * 8, Bs + (i * 256 + wave * 64) * 8);
    }
    __syncthreads();
    bf16x8 af[4], bfr[4];
#pragma unroll
    for (int mi = 0; mi < 4; ++mi)
      af[mi] = *(const bf16x8*)(As + (wr * 64 + mi * 16 + fr) * 32 + fs * 8);
#pragma unroll
    for (int ni = 0; ni < 4; ++ni)
      bfr[ni] = *(const bf16x8*)(Bs + (wc * 64 + ni * 16 + fr) * 32 + fs * 8);
#pragma unroll
    for (int mi = 0; mi < 4; ++mi)
#pragma unroll
      for (int ni = 0; ni < 4; ++ni)
        acc[mi][ni] = __builtin_amdgcn_mfma_f32_16x16x32_bf16(af[mi], bfr[ni], acc[mi][ni], 0, 0, 0);
    __syncthreads();
  }

  float* Cf = (float*)Cp + (size_t)blockIdx.z * M * N;
#pragma unroll
  for (int mi = 0; mi < 4; ++mi) {
#pragma unroll
    for (int ni = 0; ni < 4; ++ni) {
      const long col = n0 + wc * 64 + ni * 16 + fr;
#pragma unroll
      for (int r = 0; r < 4; ++r) {
        const long rowi = m0 + wr * 64 + mi * 16 + fq * 4 + r;
        if constexpr (MODE == 0) {
          Cf[rowi * N + col] = acc[mi][ni][r];
        } else {
          const float z = acc[mi][ni][r] + bias[rowi];
          const float dtv = (z > 20.f) ? z : log1pf(__expf(z));
          ((float*)Cp)[rowi * N + col] = dtv;   // [DIN][BLT], coalesced
        }
      }
    }
  }
}

// ---------------- 256x256 8-wave GEMM, 3-stage pipeline, 1 barrier/tile --------
// C[m][n] = sum_k A[m][k]*B[n][k]; A/B k-stride = Kfull; K-slice = blockIdx.y.
// OUTBF=1: bf16 out [M][N]. OUTBF=0: f32 out [z][M][N] partials.
// LDS 48KB (3 bufs) -> 3 blocks/CU. stage(t+2) issued at tile-t top: load
// in-flight ~2 tile-walls > HBM latency. Counted lgkmcnt(4)/vmcnt(4).
template<int OUTBF>
__global__ __launch_bounds__(512, 6) void gemm256(
    const u16* __restrict__ A, const u16* __restrict__ B, void* __restrict__ Cp,
    int M, int N, int Kfull, int Ksub)
{
  __shared__ __align__(16) u16 lds[3][2][8192];  // [buf][A=0/B=1][256 rows][32 k]
  const int tid = threadIdx.x;
  const int lane = tid & 63;
  const int wid = tid >> 6;
  const int wm = wid >> 2;
  const int wn = wid & 3;
  const int fr = lane & 15;
  const int fq = lane >> 4;
  const int fs = fq ^ bsw(fr);

  // XCD-aware swizzle over grid.x
  const int nbx = N >> 8;
  const int cpx = gridDim.x >> 3;
  const int bid = blockIdx.x;
  const int swz = (bid & 7) * cpx + (bid >> 3);
  const long m0 = (long)(swz / nbx) << 8;
  const long n0 = (long)(swz % nbx) << 8;
  const long kbase = (long)blockIdx.y * Ksub;

  const int srow = tid >> 2;
  const int sseg = (tid & 3) ^ bsw(srow);
  const u16* ag0 = A + (m0 + srow) * (long)Kfull + kbase + sseg * 8;
  const u16* ag1 = ag0 + 128 * (long)Kfull;
  const u16* bg0 = B + (n0 + srow) * (long)Kfull + kbase + sseg * 8;
  const u16* bg1 = bg0 + 128 * (long)Kfull;

  auto stage = [&](int c, int koff) {
    gl_lds16(ag0 + koff, &lds[c][0][tid * 8]);
    gl_lds16(ag1 + koff, &lds[c][0][4096 + tid * 8]);
    gl_lds16(bg0 + koff, &lds[c][1][tid * 8]);
    gl_lds16(bg1 + koff, &lds[c][1][4096 + tid * 8]);
  };

  const int NT = Ksub >> 5;
  stage(0, 0);
  stage(1, 32);
  asm volatile("s_waitcnt vmcnt(4)" ::: "memory");  // tile0 landed
  __builtin_amdgcn_s_barrier();

  f32x4v acc[8][4];
#pragma unroll
  for (int i = 0; i < 8; ++i)
#pragma unroll
    for (int j = 0; j < 4; ++j) acc[i][j] = (f32x4v){0.f, 0.f, 0.f, 0.f};

  const int aoff = (wm * 128 + fr) * 32 + fs * 8;
  const int boff = (wn * 64 + fr) * 32 + fs * 8;
  bf16x8 af[4], bfg[4], al[4];

  int c = 0, cs = 2;
  for (int t = 0; t < NT; ++t) {
    const u16* Asl = &lds[c][0][0];
    const u16* Bsl = &lds[c][1][0];
    if (t + 2 < NT) stage(cs, (t + 2) * 32);   // issue early: ~2 tile-walls in flight
    // 12 ds_reads for this tile (A-upper, B, A-lower)
#pragma unroll
    for (int mi = 0; mi < 4; ++mi) af[mi] = *(const bf16x8*)(Asl + aoff + mi * 512);
#pragma unroll
    for (int ni = 0; ni < 4; ++ni) bfg[ni] = *(const bf16x8*)(Bsl + boff + ni * 512);
#pragma unroll
    for (int mi = 0; mi < 4; ++mi) al[mi] = *(const bf16x8*)(Asl + aoff + 2048 + mi * 512);
    asm volatile("s_waitcnt lgkmcnt(4)" ::: "memory");  // first 8 (af,bfg) done
    __builtin_amdgcn_sched_barrier(0);
    __builtin_amdgcn_s_setprio(1);
#pragma unroll
    for (int mi = 0; mi < 4; ++mi)
#pragma unroll
      for (int ni = 0; ni < 4; ++ni)
        acc[mi][ni] = __builtin_amdgcn_mfma_f32_16x16x32_bf16(af[mi], bfg[ni], acc[mi][ni], 0, 0, 0);
    __builtin_amdgcn_s_setprio(0);
    asm volatile("s_waitcnt lgkmcnt(0)" ::: "memory");  // al done (hid under MFMA)
    __builtin_amdgcn_sched_barrier(0);
    __builtin_amdgcn_s_setprio(1);
#pragma unroll
    for (int mi = 0; mi < 4; ++mi)
#pragma unroll
      for (int ni = 0; ni < 4; ++ni)
        acc[mi + 4][ni] = __builtin_amdgcn_mfma_f32_16x16x32_bf16(al[mi], bfg[ni], acc[mi + 4][ni], 0, 0, 0);
    __builtin_amdgcn_s_setprio(0);
    if (t + 2 < NT) {
      asm volatile("s_waitcnt vmcnt(4)" ::: "memory");  // t+1 landed; t+2 in flight
    } else {
      asm volatile("s_waitcnt vmcnt(0)" ::: "memory");  // drain tail
    }
    __builtin_amdgcn_s_barrier();   // all waves: reads of buf c done + t+1 data visible
    c = (c == 2) ? 0 : c + 1;
    cs = (cs == 2) ? 0 : cs + 1;
  }

  float* Cf = (float*)Cp + (size_t)blockIdx.y * M * N;
#pragma unroll
  for (int mi = 0; mi < 8; ++mi) {
#pragma unroll
    for (int ni = 0; ni < 4; ++ni) {
      const long col = n0 + wn * 64 + ni * 16 + fr;
      const long rbase = m0 + wm * 128 + mi * 16 + fq * 4;
#pragma unroll
      for (int r = 0; r < 4; ++r) {
        if constexpr (OUTBF) {
          ((u16*)Cp)[(rbase + r) * N + col] = f2b(acc[mi][ni][r]);
        } else {
          Cf[(rbase + r) * N + col] = acc[mi][ni][r];
        }
      }
    }
  }
}

// ---------------- causal depthwise conv (K=4) + SiLU, proj(bf16) -> x(bf16) ------
__global__ __launch_bounds__(256) void conv_silu_kernel(
    const u16* __restrict__ proj, const float* __restrict__ conv_w,
    const float* __restrict__ conv_b, u16* __restrict__ xb)
{
  const int idx = blockIdx.x * 256 + threadIdx.x;
  const int tok = idx >> 11;
  const int dq = (idx & 2047) << 2;
  const int l = tok & (LSEQ - 1);
  f32x4v cb = *(const f32x4v*)(conv_b + dq);
  float a0 = cb[0], a1 = cb[1], a2 = cb[2], a3 = cb[3];
  f32x4v w0 = *(const f32x4v*)(conv_w + (size_t)(dq + 0) * 4);
  f32x4v w1 = *(const f32x4v*)(conv_w + (size_t)(dq + 1) * 4);
  f32x4v w2 = *(const f32x4v*)(conv_w + (size_t)(dq + 2) * 4);
  f32x4v w3 = *(const f32x4v*)(conv_w + (size_t)(dq + 3) * 4);
#pragma unroll
  for (int j = 0; j < 4; ++j) {
    const int lj = l - 3 + j;
    if (lj >= 0) {
      ushort4 xv = *(const ushort4*)(proj + (size_t)(tok - 3 + j) * 16384 + dq);
      a0 = fmaf(w0[j], b2f(xv.x), a0);
      a1 = fmaf(w1[j], b2f(xv.y), a1);
      a2 = fmaf(w2[j], b2f(xv.z), a2);
      a3 = fmaf(w3[j], b2f(xv.w), a3);
    }
  }
  ushort4 o;
  o.x = f2b(a0 / (1.f + __expf(-a0)));
  o.y = f2b(a1 / (1.f + __expf(-a1)));
  o.z = f2b(a2 / (1.f + __expf(-a2)));
  o.w = f2b(a3 / (1.f + __expf(-a3)));
  *(ushort4*)(xb + (size_t)tok * DIN + dq) = o;
}

// ---------------- x [2048][8192] -> x_T [8192][2048] (4x4 register transpose) ----
__global__ __launch_bounds__(256) void transpose_x_kernel(
    const u16* __restrict__ in, u16* __restrict__ outp)
{
  const int t = threadIdx.x;
  const int sr = t >> 4, sc = t & 15;
  const long r0 = (long)blockIdx.x * 64 + sr * 4;
  const long c0 = (long)blockIdx.y * 64 + sc * 4;
  ushort4 v[4];
#pragma unroll
  for (int i = 0; i < 4; ++i)
    v[i] = *(const ushort4*)(in + (r0 + i) * DIN + c0);
#pragma unroll
  for (int i = 0; i < 4; ++i) {
    ushort4 o;
    o.x = ((const u16*)&v[0])[i];
    o.y = ((const u16*)&v[1])[i];
    o.z = ((const u16*)&v[2])[i];
    o.w = ((const u16*)&v[3])[i];
    *(ushort4*)(outp + (c0 + i) * BLT + r0) = o;
  }
}

// ---------------- RMS norms; input = 8 split-K partials of ssm ----------------
__global__ __launch_bounds__(64) void rms_kernel(
    const float* __restrict__ part, u16* __restrict__ tsb,
    float* __restrict__ Bn, float* __restrict__ Cn)
{
  const int tok = blockIdx.x;
  const int lane = threadIdx.x;
  const size_t rowoff = (size_t)tok * 384;
  f32x4v t = (f32x4v){0.f, 0.f, 0.f, 0.f};
#pragma unroll
  for (int s = 0; s < 8; ++s)
    t += *(const f32x4v*)(part + (size_t)s * (BLT * 384) + rowoff + lane * 4);
  float ss = t[0]*t[0] + t[1]*t[1] + t[2]*t[2] + t[3]*t[3];
#pragma unroll
  for (int o = 32; o; o >>= 1) ss += __shfl_xor(ss, o);
  const float sc = rsqrtf(ss * (1.f / 256.f) + 1e-6f);
  ushort4 o4;
  o4.x = f2b(t[0] * sc); o4.y = f2b(t[1] * sc);
  o4.z = f2b(t[2] * sc); o4.w = f2b(t[3] * sc);
  *(ushort4*)(tsb + (size_t)tok * 256 + lane * 4) = o4;

  float v = 0.f;
  if (lane < 32) {
#pragma unroll
    for (int s = 0; s < 8; ++s)
      v += part[(size_t)s * (BLT * 384) + rowoff + 256 + lane];
  }
  float g = v * v;
#pragma unroll
  for (int o = 1; o < 16; o <<= 1) g += __shfl_xor(g, o);
  const float scBC = rsqrtf(g * (1.f / 16.f) + 1e-6f);
  if (lane < 16) Bn[(size_t)tok * 16 + lane] = v * scBC;
  else if (lane < 32) Cn[(size_t)tok * 16 + (lane - 16)] = v * scBC;
}

// ---------------- chunked scan phase 1: per-chunk partials (E, S) ----------------
__global__ __launch_bounds__(256) void scan_p1_kernel(
    const float* __restrict__ dtT, const u16* __restrict__ xT,
    const float* __restrict__ Bn, const float* __restrict__ A_log,
    float* __restrict__ partE, float* __restrict__ partS)
{
  __shared__ float Bsh[CL][16];
  const int tid = threadIdx.x;
  const int chunk = blockIdx.y;
  const int d = blockIdx.x * 64 + (tid >> 2);
  const int ln = tid & 3;
  const int tok0 = chunk * CL;
  {
    const int tt = tid >> 2, q = tid & 3;
    *(f32x4v*)&Bsh[tt][q * 4] = *(const f32x4v*)(Bn + (size_t)(tok0 + tt) * 16 + q * 4);
  }
  __syncthreads();
  float a[4];
#pragma unroll
  for (int j = 0; j < 4; ++j) a[j] = -__expf(A_log[(size_t)d * 16 + ln * 4 + j]);
  float E0 = 1.f, E1 = 1.f, E2 = 1.f, E3 = 1.f;
  float S0 = 0.f, S1 = 0.f, S2 = 0.f, S3 = 0.f;
  const float* dtp = dtT + (size_t)d * BLT + tok0;
  const u16* xp = xT + (size_t)d * BLT + tok0;
  for (int l = 0; l < CL; l += 4) {
    f32x4v dt4 = *(const f32x4v*)(dtp + l);
    ushort4 u4 = *(const ushort4*)(xp + l);
#pragma unroll
    for (int i = 0; i < 4; ++i) {
      const float dt = dt4[i];
      const float u = b2f(((const u16*)&u4)[i]);
      const float dtu = dt * u;
      f32x4v Bv = *(const f32x4v*)&Bsh[l + i][ln * 4];
      const float e0 = __expf(dt * a[0]);
      const float e1 = __expf(dt * a[1]);
      const float e2 = __expf(dt * a[2]);
      const float e3 = __expf(dt * a[3]);
      S0 = fmaf(S0, e0, dtu * Bv[0]); E0 *= e0;
      S1 = fmaf(S1, e1, dtu * Bv[1]); E1 *= e1;
      S2 = fmaf(S2, e2, dtu * Bv[2]); E2 *= e2;
      S3 = fmaf(S3, e3, dtu * Bv[3]); E3 *= e3;
    }
  }
  const size_t off = (size_t)chunk * (DIN * 16) + (size_t)d * 16 + ln * 4;
  f32x4v Ev = {E0, E1, E2, E3}, Sv = {S0, S1, S2, S3};
  *(f32x4v*)(partE + off) = Ev;
  *(f32x4v*)(partS + off) = Sv;
}

// ---------------- chunked scan phase 2: combine chunk partials ----------------
__global__ __launch_bounds__(256) void scan_p2_kernel(
    const float* __restrict__ partE, float* __restrict__ partS)
{
  const int dn = blockIdx.x * 256 + threadIdx.x;
  float s = 0.f;
  for (int c = 0; c < NCG; ++c) {
    if ((c & 15) == 0) s = 0.f;  // batch boundary reset
    const size_t off = (size_t)c * (DIN * 16) + dn;
    const float e = partE[off];
    const float ps = partS[off];
    partS[off] = s;
    s = fmaf(e, s, ps);
  }
}

// ---------------- chunked scan phase 3: re-scan with true init, emit y ----------
__global__ __launch_bounds__(256) void scan_p3_kernel(
    const float* __restrict__ dtT, const u16* __restrict__ xT,
    const float* __restrict__ Bn, const float* __restrict__ Cn,
    const float* __restrict__ A_log, const float* __restrict__ Dv,
    const float* __restrict__ stateIn, const u16* __restrict__ proj,
    u16* __restrict__ yg)
{
  __shared__ float Bsh[CL][16], Csh[CL][16];
  const int tid = threadIdx.x;
  const int chunk = blockIdx.y;
  const int d = blockIdx.x * 64 + (tid >> 2);
  const int ln = tid & 3;
  const int tok0 = chunk * CL;
  {
    const int tt = tid >> 2, q = tid & 3;
    *(f32x4v*)&Bsh[tt][q * 4] = *(const f32x4v*)(Bn + (size_t)(tok0 + tt) * 16 + q * 4);
    *(f32x4v*)&Csh[tt][q * 4] = *(const f32x4v*)(Cn + (size_t)(tok0 + tt) * 16 + q * 4);
  }
  __syncthreads();
  float a[4];
#pragma unroll
  for (int j = 0; j < 4; ++j) a[j] = -__expf(A_log[(size_t)d * 16 + ln * 4 + j]);
  f32x4v sv = *(const f32x4v*)(stateIn + (size_t)chunk * (DIN * 16) + (size_t)d * 16 + ln * 4);
  float S0 = sv[0], S1 = sv[1], S2 = sv[2], S3 = sv[3];
  const float Dd = Dv[d];
  const float* dtp = dtT + (size_t)d * BLT + tok0;
  const u16* xp = xT + (size_t)d * BLT + tok0;
  for (int l = 0; l < CL; l += 4) {
    f32x4v dt4 = *(const f32x4v*)(dtp + l);
    ushort4 u4 = *(const ushort4*)(xp + l);
#pragma unroll
    for (int i = 0; i < 4; ++i) {
      const float dt = dt4[i];
      const float u = b2f(((const u16*)&u4)[i]);
      const float dtu = dt * u;
      f32x4v Bv = *(const f32x4v*)&Bsh[l + i][ln * 4];
      f32x4v Cv = *(const f32x4v*)&Csh[l + i][ln * 4];
      const float e0 = __expf(dt * a[0]);
      const float e1 = __expf(dt * a[1]);
      const float e2 = __expf(dt * a[2]);
      const float e3 = __expf(dt * a[3]);
      float y;
      S0 = fmaf(S0, e0, dtu * Bv[0]); y = S0 * Cv[0];
      S1 = fmaf(S1, e1, dtu * Bv[1]); y = fmaf(S1, Cv[1], y);
      S2 = fmaf(S2, e2, dtu * Bv[2]); y = fmaf(S2, Cv[2], y);
      S3 = fmaf(S3, e3, dtu * Bv[3]); y = fmaf(S3, Cv[3], y);
      y += __shfl_xor(y, 1);
      y += __shfl_xor(y, 2);
      if (ln == 0) {
        const long tok = tok0 + l + i;
        const float yt = fmaf(u, Dd, y);
        const float gt = b2f(proj[tok * 16384 + DIN + d]);
        const float sg = gt / (1.f + __expf(-gt));
        yg[tok * DIN + d] = f2b(yt * sg);
      }
    }
  }
}

extern "C" void kernel_launch(void* const* d_in, const int* in_sizes, int n_in,
                              void* d_out, int out_size, void* d_ws, size_t ws_size,
                              hipStream_t stream) {
  const float* hs     = (const float*)d_in[0];
  const float* W_in   = (const float*)d_in[1];
  const float* conv_w = (const float*)d_in[2];
  const float* conv_b = (const float*)d_in[3];
  const float* W_x    = (const float*)d_in[4];
  const float* W_dt   = (const float*)d_in[5];
  const float* b_dt   = (const float*)d_in[6];
  const float* A_log  = (const float*)d_in[7];
  const float* Dv     = (const float*)d_in[8];
  const float* W_out  = (const float*)d_in[9];
  float* out = (float*)d_out;

  char* ws = (char*)d_ws;
  size_t off = 0;
  auto alloc = [&](size_t bytes) -> char* {
    char* p = ws + off;
    off += (bytes + 255) & ~(size_t)255;
    return p;
  };

  u16* W_in_b = (u16*)alloc(134217728);                // R1: W_in_bf16 -> dt_T + W_out_b
  u16* hs_b = (u16*)alloc(16777216);                   // R2: hs_bf16 -> ts/Bn/Cn/W_dt
  u16* proj_b = (u16*)alloc((size_t)BLT * 16384 * 2);  // 67MB; after scan: out_part[2]
  u16* x_b    = (u16*)alloc((size_t)BLT * DIN * 2);    // 33.5MB; after ssm: partE+partS
  u16* W_xp_b = (u16*)alloc((size_t)384 * DIN * 2);    // 6.3MB
  u16* yg_b   = (u16*)alloc((size_t)BLT * DIN * 2);    // 33.5MB; pre-scan: ssm_part[8]
  u16* x_T    = (u16*)alloc((size_t)BLT * DIN * 2);    // 33.5MB [DIN][BLT]

  float* dt_T    = (float*)W_in_b;                     // [DIN][BLT] f32, 67MB
  u16*   W_out_b = (u16*)((char*)W_in_b + 67108864);
  u16*   ts_b    = (u16*)((char*)hs_b + 3145728);
  float* Bn      = (float*)((char*)hs_b + 3145728 + 1048576);
  float* Cn      = (float*)((char*)hs_b + 3145728 + 1048576 + 131072);
  u16*   W_dt_b  = (u16*)((char*)hs_b + 3145728 + 1048576 + 262144);
  float* partE   = (float*)x_b;
  float* partS   = (float*)((char*)x_b + 16777216);
  float* ssm_part= (float*)yg_b;                       // [8][2048][384] = 25.2MB
  float* out_part= (float*)proj_b;                     // [2][2048][4096] = 67MB

  const int CG = 2048;
  // 1) convert GEMM1 operands
  cvt_kernel<<<CG, 256, 0, stream>>>(W_in, W_in_b, 67108864L);
  cvt_kernel<<<CG, 256, 0, stream>>>(hs, hs_b, 8388608L);
  // 2) proj = hs @ W_in^T  (2048 x 16384, K=4096), bf16 out
  gemm256<1><<<dim3((16384 / 256) * (BLT / 256), 1), 512, 0, stream>>>(hs_b, W_in_b, proj_b, BLT, 16384, 4096, 4096);
  // 3) convert remaining weights
  cvt_kernel<<<CG, 256, 0, stream>>>(W_out, W_out_b, 33554432L);
  cvt_kernel<<<CG, 256, 0, stream>>>(W_dt, W_dt_b, 2097152L);
  cvt_pad_kernel<<<CG, 256, 0, stream>>>(W_x, W_xp_b, 288, DIN, (long)384 * DIN);
  // 4) conv + silu -> x (bf16)
  conv_silu_kernel<<<16384, 256, 0, stream>>>(proj_b, conv_w, conv_b, x_b);
  // 5) x_T = transpose(x)  [DIN][BLT]
  transpose_x_kernel<<<dim3(BLT / 64, DIN / 64), 256, 0, stream>>>(x_b, x_T);
  // 6) ssm partials: x @ W_x^T split-K=8 (Klen=1024), f32 partials in ssm_part
  gemm_bt<0><<<dim3(384 / 128, BLT / 128, 8), 256, 0, stream>>>(x_b, W_xp_b, ssm_part, BLT, 384, 1024, DIN, nullptr);
  // 7) rms norms (reduces the 8 partials)
  rms_kernel<<<BLT, 64, 0, stream>>>(ssm_part, ts_b, Bn, Cn);
  // 8) dt_T[d][tok] = softplus(W_dt @ ts^T + b_dt[d]) — A=W_dt (M=8192), coalesced
  gemm_bt<3><<<dim3(BLT / 128, DIN / 128), 256, 0, stream>>>(W_dt_b, ts_b, dt_T, DIN, BLT, 256, 256, b_dt);
  // 9) chunked scan
  scan_p1_kernel<<<dim3(DIN / 64, NCG), 256, 0, stream>>>(dt_T, x_T, Bn, A_log, partE, partS);
  scan_p2_kernel<<<DIN * 16 / 256, 256, 0, stream>>>(partE, partS);
  scan_p3_kernel<<<dim3(DIN / 64, NCG), 256, 0, stream>>>(dt_T, x_T, Bn, Cn, A_log, Dv, partS, proj_b, yg_b);
  // 10) out = ygated @ W_out^T split-K=2 (256 blocks), f32 partials then add
  gemm256<0><<<dim3((HH / 256) * (BLT / 256), 2), 512, 0, stream>>>(yg_b, W_out_b, out_part, BLT, HH, DIN, DIN / 2);
  add2_kernel<<<CG, 256, 0, stream>>>(out_part, out_part + (size_t)BLT * HH, out, (long)BLT * HH);
}